// Round 2
// baseline (3959.510 us; speedup 1.0000x reference)
//
#include <hip/hip_runtime.h>
#include <math.h>

#define DI __device__ __forceinline__

// Problem constants
// PL=8 LAT=96 LON=180 C=192 H=6 D=32 ; windows (2,6,12) shift (1,3,6)
// NPL=4 NLAT=16 NLON=15 NW=64 N=144 L=138240
constexpr int L_TOK   = 138240;
constexpr float QSCALE = 0.17677669529663687f; // 32^-0.5

DI void ld4(float* d, const float* s) {
    float4 t = *(const float4*)s; d[0]=t.x; d[1]=t.y; d[2]=t.z; d[3]=t.w;
}
DI void st4(float* d, const float* s) {
    float4 t; t.x=s[0]; t.y=s[1]; t.z=s[2]; t.w=s[3]; *(float4*)d = t;
}

// windowed row -> original token offset (*192), applying forward roll (-1,-3,-6)
DI int src_off(int row) {
    int bl  = row / 9216;  int rem = row - bl * 9216;   // 9216 = 64*144
    int wi  = rem / 144;   int n   = rem - wi * 144;
    int npl = wi >> 4,     nlat = wi & 15;
    int w0  = n / 72;      int rn = n - w0 * 72;
    int w1  = rn / 12;     int w2 = rn - w1 * 12;
    int pl = npl * 2 + w0 + 1;  if (pl >= 8)   pl -= 8;
    int la = nlat * 6 + w1 + 3; if (la >= 96)  la -= 96;
    int lo = bl * 12 + w2 + 6;  if (lo >= 180) lo -= 180;
    return ((pl * 96 + la) * 180 + lo) * 192;
}

DI float gelu_exact(float v) {
    return 0.5f * v * (1.0f + erff(v * 0.70710678118654752440f));
}

// ---------------------------------------------------------------------------
// QKV: rows = windowed tokens (LN1 fused, gathered from x), K=192, N=576
// out: q/k/v tiled [bl][h][w][n][d]; q scaled by D^-0.5 after bias
// ---------------------------------------------------------------------------
__global__ __launch_bounds__(256) void qkv_ln_kernel(
    const float* __restrict__ x,
    const float* __restrict__ ln1w, const float* __restrict__ ln1b,
    const float* __restrict__ w,    const float* __restrict__ bias,
    float* __restrict__ qo, float* __restrict__ ko, float* __restrict__ vo)
{
    __shared__ float As[64][196];   // LN'd A tile, 64 rows x 192 (pad 196)
    __shared__ float Ws[32][64];
    __shared__ float lw[192], lb[192];
    __shared__ float s_mu[64], s_rs[64];
    __shared__ int   s_src[64];

    const int t  = threadIdx.x;
    const int m0 = blockIdx.x * 64;

    if (t < 192) { lw[t] = ln1w[t]; lb[t] = ln1b[t]; }
    if (t < 64)  { s_src[t] = src_off(m0 + t); }
    __syncthreads();

    // per-row LN stats: 4 threads per row
    {
        int r = t >> 2, p = t & 3;
        const float* xr = x + s_src[r] + p * 48;
        float s = 0.f, s2 = 0.f;
        #pragma unroll
        for (int i = 0; i < 12; i++) {
            float4 v = *(const float4*)(xr + i * 4);
            s  += v.x + v.y + v.z + v.w;
            s2 += v.x*v.x + v.y*v.y + v.z*v.z + v.w*v.w;
        }
        s  += __shfl_xor(s, 1);  s  += __shfl_xor(s, 2);
        s2 += __shfl_xor(s2, 1); s2 += __shfl_xor(s2, 2);
        if (p == 0) {
            float mu  = s * (1.f / 192.f);
            float var = s2 * (1.f / 192.f) - mu * mu;
            s_mu[r] = mu;
            s_rs[r] = 1.0f / sqrtf(var + 1e-5f);
        }
    }
    __syncthreads();

    // stage LN'd A tile (full K)
    for (int V = t; V < 3072; V += 256) {
        int r = V / 48, c4 = (V - (V / 48) * 48) * 4;
        float a[4]; ld4(a, x + s_src[r] + c4);
        float mu = s_mu[r], rs = s_rs[r];
        float o[4];
        #pragma unroll
        for (int j = 0; j < 4; j++) o[j] = (a[j] - mu) * rs * lw[c4 + j] + lb[c4 + j];
        st4(&As[r][c4], o);
    }
    __syncthreads();

    const int ty = t >> 4, tx = t & 15;
    const int r0 = ty * 4, c0 = tx * 4;

    // per-thread output row bases (tiled layout, without h term)
    int rb[4];
    #pragma unroll
    for (int i = 0; i < 4; i++) {
        int row = m0 + r0 + i;
        int bl = row / 9216; int rem = row - bl * 9216;
        int wi = rem / 144;  int n = rem - wi * 144;
        rb[i] = bl * 1769472 + wi * 4608 + n * 32;   // ((bl*6+h)*64+wi)*4608 + n*32 + d
    }

    for (int nc = 0; nc < 9; nc++) {
        float acc[4][4] = {};
        for (int kc = 0; kc < 6; kc++) {
            __syncthreads();
            {
                int kr = t >> 4, c4 = (t & 15) * 4;
                #pragma unroll
                for (int it = 0; it < 2; it++) {
                    int krr = kr + it * 16;
                    *(float4*)(&Ws[krr][c4]) =
                        *(const float4*)(w + (kc * 32 + krr) * 576 + nc * 64 + c4);
                }
            }
            __syncthreads();
            const int kb = kc * 32;
            #pragma unroll
            for (int kk = 0; kk < 32; kk += 4) {
                float a[4][4];
                ld4(a[0], &As[r0 + 0][kb + kk]);
                ld4(a[1], &As[r0 + 1][kb + kk]);
                ld4(a[2], &As[r0 + 2][kb + kk]);
                ld4(a[3], &As[r0 + 3][kb + kk]);
                #pragma unroll
                for (int jk = 0; jk < 4; jk++) {
                    float b4[4]; ld4(b4, &Ws[kk + jk][c0]);
                    #pragma unroll
                    for (int i = 0; i < 4; i++)
                        #pragma unroll
                        for (int j = 0; j < 4; j++)
                            acc[i][j] += a[i][jk] * b4[j];
                }
            }
        }
        // epilogue: split into q/k/v tiled layout (64-col tiles never straddle 192)
        int c   = nc * 64 + c0;         // 0..575
        int buf = c / 192;
        int cc  = c - buf * 192;
        int h   = cc >> 5, d = cc & 31;
        float* outp = (buf == 0) ? qo : ((buf == 1) ? ko : vo);
        float sc = (buf == 0) ? QSCALE : 1.0f;
        float b4[4]; ld4(b4, bias + c);
        #pragma unroll
        for (int i = 0; i < 4; i++) {
            float o4[4];
            #pragma unroll
            for (int j = 0; j < 4; j++) o4[j] = (acc[i][j] + b4[j]) * sc;
            st4(outp + rb[i] + h * 294912 + d, o4);
        }
    }
}

// ---------------------------------------------------------------------------
// Attention: one block per (bl, h, w). 144x144 scores in LDS.
// bias index + shift mask computed analytically. O overwrites q tile in-place.
// ---------------------------------------------------------------------------
__global__ __launch_bounds__(256) void attn_kernel(
    const float* __restrict__ qb, const float* __restrict__ kb,
    const float* __restrict__ vb, const float* __restrict__ bt,
    float* __restrict__ ob)
{
    __shared__ float qs[144][36], ks[144][36], vs[144][36];
    __shared__ float S[144][144];
    __shared__ int   eq[144], em[144], cnt[144];
    __shared__ float rinv[144];

    const int t   = threadIdx.x;
    const int bid = blockIdx.x;              // ((bl*6 + h)*64 + w)
    const int wi  = bid & 63;
    const int bh  = bid >> 6;
    const int h   = bh % 6;
    const int bl  = bh / 6;
    const int tb  = bid * 4608;

    for (int V = t; V < 1152; V += 256) {
        int r = V >> 3, c4 = (V & 7) * 4;
        *(float4*)(&qs[r][c4]) = *(const float4*)(qb + tb + r * 32 + c4);
        *(float4*)(&ks[r][c4]) = *(const float4*)(kb + tb + r * 32 + c4);
        *(float4*)(&vs[r][c4]) = *(const float4*)(vb + tb + r * 32 + c4);
    }
    if (t < 144) {
        int n = t;
        int w0 = n / 72; int rn = n - w0 * 72;
        int w1 = rn / 12; int w2 = rn - w1 * 12;
        eq[t] = 828 * w0 + 23 * w1 + w2;                     // q-side EPI terms
        em[t] = 1656 * w0 + 138 * w1 + 12 * w2 + 11;         // k-side EPI terms
        int npl = wi >> 4, nlat = wi & 15;
        int p0 = npl * 2 + w0, p1 = nlat * 6 + w1, p2 = bl * 12 + w2;
        int sa = (p0 < 6) ? 0 : ((p0 < 7) ? 1 : 2);
        int sb = (p1 < 90) ? 0 : ((p1 < 93) ? 1 : 2);
        int sc = (p2 < 174) ? 0 : 1;
        cnt[t] = sa * 9 + sb * 3 + sc;
    }
    __syncthreads();

    const int ty = t >> 4, tx = t & 15;
    const int wh = wi * 6 + h;

    // S = q k^T (+bias +mask), 48x48 tile steps, 3x3 micro
    for (int st = 0; st < 9; st++) {
        int r0 = (st / 3) * 48 + ty * 3;
        int c0 = (st % 3) * 48 + tx * 3;
        float acc[3][3] = {};
        #pragma unroll
        for (int kk = 0; kk < 32; kk += 4) {
            float a[3][4], b[3][4];
            ld4(a[0], &qs[r0 + 0][kk]); ld4(a[1], &qs[r0 + 1][kk]); ld4(a[2], &qs[r0 + 2][kk]);
            ld4(b[0], &ks[c0 + 0][kk]); ld4(b[1], &ks[c0 + 1][kk]); ld4(b[2], &ks[c0 + 2][kk]);
            #pragma unroll
            for (int jk = 0; jk < 4; jk++)
                #pragma unroll
                for (int i = 0; i < 3; i++)
                    #pragma unroll
                    for (int j = 0; j < 3; j++)
                        acc[i][j] += a[i][jk] * b[j][jk];
        }
        #pragma unroll
        for (int i = 0; i < 3; i++) {
            int r = r0 + i; int cr = cnt[r]; int eqr = eq[r];
            #pragma unroll
            for (int j = 0; j < 3; j++) {
                int cm = c0 + j;
                float bv = bt[(eqr + em[cm]) * 384 + wh];
                float mv = (cr == cnt[cm]) ? 0.f : -100.f;
                S[r][cm] = acc[i][j] + bv + mv;
            }
        }
    }
    __syncthreads();

    if (t < 144) {
        float mx = -1e30f;
        for (int j = 0; j < 144; j++) mx = fmaxf(mx, S[t][j]);
        float sum = 0.f;
        for (int j = 0; j < 144; j++) {
            float e = __expf(S[t][j] - mx);
            S[t][j] = e; sum += e;
        }
        rinv[t] = 1.0f / sum;
    }
    __syncthreads();

    // O = P V  (rows 9/thread, cols 2/thread)
    {
        int r0 = ty * 9, cd = tx * 2;
        float acc[9][2] = {};
        for (int m = 0; m < 144; m += 2) {
            float2 v0 = *(const float2*)(&vs[m][cd]);
            float2 v1 = *(const float2*)(&vs[m + 1][cd]);
            #pragma unroll
            for (int i = 0; i < 9; i++) {
                float2 p = *(const float2*)(&S[r0 + i][m]);
                acc[i][0] += p.x * v0.x + p.y * v1.x;
                acc[i][1] += p.x * v0.y + p.y * v1.y;
            }
        }
        #pragma unroll
        for (int i = 0; i < 9; i++) {
            float ri = rinv[r0 + i];
            float2 o2; o2.x = acc[i][0] * ri; o2.y = acc[i][1] * ri;
            *(float2*)(ob + tb + (r0 + i) * 32 + cd) = o2;
        }
    }
}

// ---------------------------------------------------------------------------
// Proj: rows = windowed tokens, A from tiled o, K=192, N=192 (full-N acc)
// writes xa[orig] = x[orig] + o@W + b   (inverse roll/partition scatter)
// ---------------------------------------------------------------------------
__global__ __launch_bounds__(256) void proj_kernel(
    const float* __restrict__ ot, const float* __restrict__ x,
    const float* __restrict__ w,  const float* __restrict__ pb,
    float* __restrict__ xa)
{
    __shared__ float As[64][68];
    __shared__ float Ws[64][196];
    __shared__ int s_ob[64], s_xb[64];

    const int t = threadIdx.x, m0 = blockIdx.x * 64;
    if (t < 64) {
        int row = m0 + t;
        int bl = row / 9216; int rem = row - bl * 9216;
        int wi = rem / 144;  int n = rem - wi * 144;
        s_ob[t] = bl * 1769472 + wi * 4608 + n * 32;
        s_xb[t] = src_off(row);
    }
    const int ty = t >> 4, tx = t & 15;
    const int r0 = ty * 4, c0 = tx * 4;
    float acc[3][4][4] = {};

    for (int kc = 0; kc < 3; kc++) {
        __syncthreads();
        for (int V = t; V < 1024; V += 256) {
            int r = V >> 4, kq = (V & 15) * 4;
            int k = kc * 64 + kq; int hh = k >> 5, d = k & 31;
            *(float4*)(&As[r][kq]) = *(const float4*)(ot + s_ob[r] + hh * 294912 + d);
        }
        for (int V = t; V < 3072; V += 256) {
            int kr = V / 48, c4 = (V - kr * 48) * 4;
            *(float4*)(&Ws[kr][c4]) = *(const float4*)(w + (kc * 64 + kr) * 192 + c4);
        }
        __syncthreads();
        for (int kk = 0; kk < 64; kk += 4) {
            float a[4][4];
            ld4(a[0], &As[r0 + 0][kk]); ld4(a[1], &As[r0 + 1][kk]);
            ld4(a[2], &As[r0 + 2][kk]); ld4(a[3], &As[r0 + 3][kk]);
            #pragma unroll
            for (int cc = 0; cc < 3; cc++)
                #pragma unroll
                for (int jk = 0; jk < 4; jk++) {
                    float b4[4]; ld4(b4, &Ws[kk + jk][cc * 64 + c0]);
                    #pragma unroll
                    for (int i = 0; i < 4; i++)
                        #pragma unroll
                        for (int j = 0; j < 4; j++)
                            acc[cc][i][j] += a[i][jk] * b4[j];
                }
        }
    }
    #pragma unroll
    for (int cc = 0; cc < 3; cc++) {
        int c = cc * 64 + c0;
        float b4[4]; ld4(b4, pb + c);
        #pragma unroll
        for (int i = 0; i < 4; i++) {
            int xb = s_xb[r0 + i] + c;
            float xv[4]; ld4(xv, x + xb);
            float o4[4];
            #pragma unroll
            for (int j = 0; j < 4; j++) o4[j] = acc[cc][i][j] + b4[j] + xv[j];
            st4(xa + xb, o4);
        }
    }
}

// ---------------------------------------------------------------------------
// LN2: 4 tokens per block (one wave each)
// ---------------------------------------------------------------------------
__global__ __launch_bounds__(256) void ln2_kernel(
    const float* __restrict__ xa, const float* __restrict__ w,
    const float* __restrict__ b,  float* __restrict__ y)
{
    int wv = threadIdx.x >> 6, ln = threadIdx.x & 63;
    int tok = blockIdx.x * 4 + wv;
    const float* xr = xa + tok * 192;
    float v0 = xr[ln], v1 = xr[ln + 64], v2 = xr[ln + 128];
    float s = v0 + v1 + v2, s2 = v0 * v0 + v1 * v1 + v2 * v2;
    #pragma unroll
    for (int off = 1; off < 64; off <<= 1) {
        s += __shfl_xor(s, off); s2 += __shfl_xor(s2, off);
    }
    float mu = s * (1.f / 192.f);
    float rs = 1.0f / sqrtf(s2 * (1.f / 192.f) - mu * mu + 1e-5f);
    float* yr = y + tok * 192;
    yr[ln]       = (v0 - mu) * rs * w[ln]       + b[ln];
    yr[ln + 64]  = (v1 - mu) * rs * w[ln + 64]  + b[ln + 64];
    yr[ln + 128] = (v2 - mu) * rs * w[ln + 128] + b[ln + 128];
}

// ---------------------------------------------------------------------------
// FC1 (+exact GELU): K=192, N=768, M-slice
// ---------------------------------------------------------------------------
__global__ __launch_bounds__(256) void fc1_kernel(
    const float* __restrict__ y, const float* __restrict__ w,
    const float* __restrict__ bias, float* __restrict__ tout, int slice_base)
{
    __shared__ float As[64][196];
    __shared__ float Ws[32][64];
    const int t = threadIdx.x, m0 = blockIdx.x * 64;

    for (int V = t; V < 3072; V += 256) {
        int r = V / 48, c4 = (V - (V / 48) * 48) * 4;
        *(float4*)(&As[r][c4]) = *(const float4*)(y + (slice_base + m0 + r) * 192 + c4);
    }
    __syncthreads();

    const int ty = t >> 4, tx = t & 15;
    const int r0 = ty * 4, c0 = tx * 4;

    for (int nc = 0; nc < 12; nc++) {
        float acc[4][4] = {};
        for (int kc = 0; kc < 6; kc++) {
            __syncthreads();
            {
                int kr = t >> 4, c4 = (t & 15) * 4;
                #pragma unroll
                for (int it = 0; it < 2; it++) {
                    int krr = kr + it * 16;
                    *(float4*)(&Ws[krr][c4]) =
                        *(const float4*)(w + (kc * 32 + krr) * 768 + nc * 64 + c4);
                }
            }
            __syncthreads();
            const int kb = kc * 32;
            #pragma unroll
            for (int kk = 0; kk < 32; kk += 4) {
                float a[4][4];
                ld4(a[0], &As[r0 + 0][kb + kk]);
                ld4(a[1], &As[r0 + 1][kb + kk]);
                ld4(a[2], &As[r0 + 2][kb + kk]);
                ld4(a[3], &As[r0 + 3][kb + kk]);
                #pragma unroll
                for (int jk = 0; jk < 4; jk++) {
                    float b4[4]; ld4(b4, &Ws[kk + jk][c0]);
                    #pragma unroll
                    for (int i = 0; i < 4; i++)
                        #pragma unroll
                        for (int j = 0; j < 4; j++)
                            acc[i][j] += a[i][jk] * b4[j];
                }
            }
        }
        int c = nc * 64 + c0;
        float b4[4]; ld4(b4, bias + c);
        #pragma unroll
        for (int i = 0; i < 4; i++) {
            int row = m0 + r0 + i;
            float o4[4];
            #pragma unroll
            for (int j = 0; j < 4; j++) o4[j] = gelu_exact(acc[i][j] + b4[j]);
            st4(tout + row * 768 + c, o4);
        }
    }
}

// ---------------------------------------------------------------------------
// FC2 + residual: K=768, N=192 (full-N acc), M-slice
// ---------------------------------------------------------------------------
__global__ __launch_bounds__(256) void fc2_kernel(
    const float* __restrict__ tin, const float* __restrict__ xa,
    const float* __restrict__ w,   const float* __restrict__ fb,
    float* __restrict__ out, int slice_base)
{
    __shared__ float As[64][68];
    __shared__ float Ws[64][196];
    const int t = threadIdx.x, m0 = blockIdx.x * 64;
    const int ty = t >> 4, tx = t & 15;
    const int r0 = ty * 4, c0 = tx * 4;
    float acc[3][4][4] = {};

    for (int kc = 0; kc < 12; kc++) {
        __syncthreads();
        for (int V = t; V < 1024; V += 256) {
            int r = V >> 4, kq = (V & 15) * 4;
            *(float4*)(&As[r][kq]) = *(const float4*)(tin + (m0 + r) * 768 + kc * 64 + kq);
        }
        for (int V = t; V < 3072; V += 256) {
            int kr = V / 48, c4 = (V - kr * 48) * 4;
            *(float4*)(&Ws[kr][c4]) = *(const float4*)(w + (kc * 64 + kr) * 192 + c4);
        }
        __syncthreads();
        for (int kk = 0; kk < 64; kk += 4) {
            float a[4][4];
            ld4(a[0], &As[r0 + 0][kk]); ld4(a[1], &As[r0 + 1][kk]);
            ld4(a[2], &As[r0 + 2][kk]); ld4(a[3], &As[r0 + 3][kk]);
            #pragma unroll
            for (int cc = 0; cc < 3; cc++)
                #pragma unroll
                for (int jk = 0; jk < 4; jk++) {
                    float b4[4]; ld4(b4, &Ws[kk + jk][cc * 64 + c0]);
                    #pragma unroll
                    for (int i = 0; i < 4; i++)
                        #pragma unroll
                        for (int j = 0; j < 4; j++)
                            acc[cc][i][j] += a[i][jk] * b4[j];
                }
        }
    }
    #pragma unroll
    for (int cc = 0; cc < 3; cc++) {
        int c = cc * 64 + c0;
        float b4[4]; ld4(b4, fb + c);
        #pragma unroll
        for (int i = 0; i < 4; i++) {
            int row = slice_base + m0 + r0 + i;
            int off = row * 192 + c;
            float xv[4]; ld4(xv, xa + off);
            float o4[4];
            #pragma unroll
            for (int j = 0; j < 4; j++) o4[j] = acc[cc][i][j] + b4[j] + xv[j];
            st4(out + off, o4);
        }
    }
}

// ---------------------------------------------------------------------------
extern "C" void kernel_launch(void* const* d_in, const int* in_sizes, int n_in,
                              void* d_out, int out_size, void* d_ws, size_t ws_size,
                              hipStream_t stream)
{
    const float* x      = (const float*)d_in[0];
    const float* ln1w   = (const float*)d_in[1];
    const float* ln1b   = (const float*)d_in[2];
    const float* qkvw   = (const float*)d_in[3];
    const float* qkvb   = (const float*)d_in[4];
    const float* projw  = (const float*)d_in[5];
    const float* projb  = (const float*)d_in[6];
    const float* biast  = (const float*)d_in[7];
    const float* ln2w   = (const float*)d_in[8];
    const float* ln2b   = (const float*)d_in[9];
    const float* fc1w   = (const float*)d_in[10];
    const float* fc1b   = (const float*)d_in[11];
    const float* fc2w   = (const float*)d_in[12];
    const float* fc2b   = (const float*)d_in[13];
    float* out = (float*)d_out;

    // Workspace: 2 slots of 138240*192 floats (212 MB total).
    // Third logical buffer aliases d_out (v -> y), safe under the strictly
    // sequential kernel ordering:
    //   qkv writes v->out ; attn reads v ; ln2 writes y->out ;
    //   fc1 slice s reads y rows of slice s ; fc2 slice s overwrites exactly
    //   those rows afterwards; later slices' y rows untouched until read.
    const size_t SLOT = 26542080;       // 138240*192 floats
    float* qbuf = (float*)d_ws;         // q -> o (in-place) -> fc1 intermediate slices
    float* kbuf = qbuf + SLOT;          // k -> xa (x + attn residual)
    float* vbuf = out;                  // v -> y (LN2 out) -> final out

    qkv_ln_kernel<<<2160, 256, 0, stream>>>(x, ln1w, ln1b, qkvw, qkvb, qbuf, kbuf, vbuf);
    attn_kernel<<<5760, 256, 0, stream>>>(qbuf, kbuf, vbuf, biast, qbuf);
    proj_kernel<<<2160, 256, 0, stream>>>(qbuf, x, projw, projb, kbuf);
    ln2_kernel<<<34560, 256, 0, stream>>>(kbuf, ln2w, ln2b, vbuf);
    for (int s = 0; s < 4; s++) {
        fc1_kernel<<<540, 256, 0, stream>>>(vbuf, fc1w, fc1b, qbuf, s * 34560);
        fc2_kernel<<<540, 256, 0, stream>>>(qbuf, kbuf, fc2w, fc2b, out, s * 34560);
    }
}

// Round 3
// 3257.525 us; speedup vs baseline: 1.2155x; 1.2155x over previous
//
#include <hip/hip_runtime.h>
#include <math.h>

#define DI __device__ __forceinline__

// Problem constants
// PL=8 LAT=96 LON=180 C=192 H=6 D=32 ; windows (2,6,12) shift (1,3,6)
// NPL=4 NLAT=16 NLON=15 NW=64 N=144 L=138240 ; BIAS_SIZE=3444
constexpr float QSCALE = 0.17677669529663687f; // 32^-0.5

typedef __attribute__((ext_vector_type(8))) short short8;
typedef __attribute__((ext_vector_type(4))) float f32x4;

DI void ld4(float* d, const float* s) {
    float4 t = *(const float4*)s; d[0]=t.x; d[1]=t.y; d[2]=t.z; d[3]=t.w;
}
DI void st4(float* d, const float* s) {
    float4 t; t.x=s[0]; t.y=s[1]; t.z=s[2]; t.w=s[3]; *(float4*)d = t;
}

DI unsigned short f2b(float f) {            // fp32 -> bf16 bits, RNE
    unsigned u = __builtin_bit_cast(unsigned, f);
    return (unsigned short)((u + 0x7FFFu + ((u >> 16) & 1u)) >> 16);
}

// windowed row -> original token offset (*192), applying forward roll (-1,-3,-6)
DI int src_off(int row) {
    int bl  = row / 9216;  int rem = row - bl * 9216;   // 9216 = 64*144
    int wi  = rem / 144;   int n   = rem - wi * 144;
    int npl = wi >> 4,     nlat = wi & 15;
    int w0  = n / 72;      int rn = n - w0 * 72;
    int w1  = rn / 12;     int w2 = rn - w1 * 12;
    int pl = npl * 2 + w0 + 1;  if (pl >= 8)   pl -= 8;
    int la = nlat * 6 + w1 + 3; if (la >= 96)  la -= 96;
    int lo = bl * 12 + w2 + 6;  if (lo >= 180) lo -= 180;
    return ((pl * 96 + la) * 180 + lo) * 192;
}

DI float gelu_exact(float v) {
    return 0.5f * v * (1.0f + erff(v * 0.70710678118654752440f));
}

// ---------------------------------------------------------------------------
// QKV: rows = windowed tokens (LN1 fused, gathered from x), K=192, N=576
// out: q/k/v tiled [bl][h][w][n][d]; q scaled by D^-0.5 after bias
// ---------------------------------------------------------------------------
__global__ __launch_bounds__(256) void qkv_ln_kernel(
    const float* __restrict__ x,
    const float* __restrict__ ln1w, const float* __restrict__ ln1b,
    const float* __restrict__ w,    const float* __restrict__ bias,
    float* __restrict__ qo, float* __restrict__ ko, float* __restrict__ vo)
{
    __shared__ float As[64][196];   // LN'd A tile, 64 rows x 192 (pad 196)
    __shared__ float Ws[32][64];
    __shared__ float lw[192], lb[192];
    __shared__ float s_mu[64], s_rs[64];
    __shared__ int   s_src[64];

    const int t  = threadIdx.x;
    const int m0 = blockIdx.x * 64;

    if (t < 192) { lw[t] = ln1w[t]; lb[t] = ln1b[t]; }
    if (t < 64)  { s_src[t] = src_off(m0 + t); }
    __syncthreads();

    {
        int r = t >> 2, p = t & 3;
        const float* xr = x + s_src[r] + p * 48;
        float s = 0.f, s2 = 0.f;
        #pragma unroll
        for (int i = 0; i < 12; i++) {
            float4 v = *(const float4*)(xr + i * 4);
            s  += v.x + v.y + v.z + v.w;
            s2 += v.x*v.x + v.y*v.y + v.z*v.z + v.w*v.w;
        }
        s  += __shfl_xor(s, 1);  s  += __shfl_xor(s, 2);
        s2 += __shfl_xor(s2, 1); s2 += __shfl_xor(s2, 2);
        if (p == 0) {
            float mu  = s * (1.f / 192.f);
            float var = s2 * (1.f / 192.f) - mu * mu;
            s_mu[r] = mu;
            s_rs[r] = 1.0f / sqrtf(var + 1e-5f);
        }
    }
    __syncthreads();

    for (int V = t; V < 3072; V += 256) {
        int r = V / 48, c4 = (V - (V / 48) * 48) * 4;
        float a[4]; ld4(a, x + s_src[r] + c4);
        float mu = s_mu[r], rs = s_rs[r];
        float o[4];
        #pragma unroll
        for (int j = 0; j < 4; j++) o[j] = (a[j] - mu) * rs * lw[c4 + j] + lb[c4 + j];
        st4(&As[r][c4], o);
    }
    __syncthreads();

    const int ty = t >> 4, tx = t & 15;
    const int r0 = ty * 4, c0 = tx * 4;

    int rb[4];
    #pragma unroll
    for (int i = 0; i < 4; i++) {
        int row = m0 + r0 + i;
        int bl = row / 9216; int rem = row - bl * 9216;
        int wi = rem / 144;  int n = rem - wi * 144;
        rb[i] = bl * 1769472 + wi * 4608 + n * 32;
    }

    for (int nc = 0; nc < 9; nc++) {
        float acc[4][4] = {};
        for (int kc = 0; kc < 6; kc++) {
            __syncthreads();
            {
                int kr = t >> 4, c4 = (t & 15) * 4;
                #pragma unroll
                for (int it = 0; it < 2; it++) {
                    int krr = kr + it * 16;
                    *(float4*)(&Ws[krr][c4]) =
                        *(const float4*)(w + (kc * 32 + krr) * 576 + nc * 64 + c4);
                }
            }
            __syncthreads();
            const int kb = kc * 32;
            #pragma unroll
            for (int kk = 0; kk < 32; kk += 4) {
                float a[4][4];
                ld4(a[0], &As[r0 + 0][kb + kk]);
                ld4(a[1], &As[r0 + 1][kb + kk]);
                ld4(a[2], &As[r0 + 2][kb + kk]);
                ld4(a[3], &As[r0 + 3][kb + kk]);
                #pragma unroll
                for (int jk = 0; jk < 4; jk++) {
                    float b4[4]; ld4(b4, &Ws[kk + jk][c0]);
                    #pragma unroll
                    for (int i = 0; i < 4; i++)
                        #pragma unroll
                        for (int j = 0; j < 4; j++)
                            acc[i][j] += a[i][jk] * b4[j];
                }
            }
        }
        int c   = nc * 64 + c0;
        int buf = c / 192;
        int cc  = c - buf * 192;
        int h   = cc >> 5, d = cc & 31;
        float* outp = (buf == 0) ? qo : ((buf == 1) ? ko : vo);
        float sc = (buf == 0) ? QSCALE : 1.0f;
        float b4[4]; ld4(b4, bias + c);
        #pragma unroll
        for (int i = 0; i < 4; i++) {
            float o4[4];
            #pragma unroll
            for (int j = 0; j < 4; j++) o4[j] = (acc[i][j] + b4[j]) * sc;
            st4(outp + rb[i] + h * 294912 + d, o4);
        }
    }
}

// ---------------------------------------------------------------------------
// Attention via MFMA bf16: one block (9 waves, 576 thr) per (bl, h, w).
// Wave s owns 16-row strip: 9 QK mfma -> bias+mask -> softmax (shfl within
// 16-lane groups) -> P bf16 to per-wave scratch -> 5x2 PV mfma (K padded 160).
// ---------------------------------------------------------------------------
__global__ __launch_bounds__(576, 5) void attn_kernel(
    const float* __restrict__ qb, const float* __restrict__ kb,
    const float* __restrict__ vb, const float* __restrict__ bt,
    float* __restrict__ ob)
{
    __shared__ unsigned short qlds[144 * 40];   // bf16, row stride 40
    __shared__ unsigned short klds[144 * 40];
    __shared__ unsigned short vlds[160 * 36];   // rows 144..159 zero
    __shared__ float biaslds[3444];             // bt[:, wi, h]
    __shared__ int eqa[144], ema[144], cnta[144];
    __shared__ unsigned short pscratch[9 * 640];// per-wave 16 x 40

    const int t   = threadIdx.x;
    const int bid = blockIdx.x;              // ((bl*6 + h)*64 + w)
    const int wi  = bid & 63;
    const int bh  = bid >> 6;
    const int h   = bh % 6;
    const int bl  = bh / 6;
    const int tb  = bid * 4608;
    const int wh  = wi * 6 + h;

    // stage q/k/v fp32 -> bf16 LDS
    for (int idx = t; idx < 1152; idx += 576) {
        int r = idx >> 3, q4 = (idx & 7) * 4;
        float4 qv = *(const float4*)(qb + tb + r * 32 + q4);
        float4 kv = *(const float4*)(kb + tb + r * 32 + q4);
        float4 vv = *(const float4*)(vb + tb + r * 32 + q4);
        ushort4 qp; qp.x=f2b(qv.x); qp.y=f2b(qv.y); qp.z=f2b(qv.z); qp.w=f2b(qv.w);
        ushort4 kp; kp.x=f2b(kv.x); kp.y=f2b(kv.y); kp.z=f2b(kv.z); kp.w=f2b(kv.w);
        ushort4 vp; vp.x=f2b(vv.x); vp.y=f2b(vv.y); vp.z=f2b(vv.z); vp.w=f2b(vv.w);
        *(ushort4*)(&qlds[r * 40 + q4]) = qp;
        *(ushort4*)(&klds[r * 40 + q4]) = kp;
        *(ushort4*)(&vlds[r * 36 + q4]) = vp;
    }
    vlds[144 * 36 + t] = 0;                      // 16*36 = 576 pad elems
    for (int e = t; e < 3444; e += 576) biaslds[e] = bt[e * 384 + wh];
    if (t < 144) {
        int n = t;
        int w0 = n / 72; int rn = n - w0 * 72;
        int w1 = rn / 12; int w2 = rn - w1 * 12;
        eqa[t] = 828 * w0 + 23 * w1 + w2;
        ema[t] = 1656 * w0 + 138 * w1 + 12 * w2 + 11;
        int npl = wi >> 4, nlat = wi & 15;
        int p0 = npl * 2 + w0, p1 = nlat * 6 + w1, p2 = bl * 12 + w2;
        int sa = (p0 < 6) ? 0 : ((p0 < 7) ? 1 : 2);
        int sb = (p1 < 90) ? 0 : ((p1 < 93) ? 1 : 2);
        int sc = (p2 < 174) ? 0 : 1;
        cnta[t] = sa * 9 + sb * 3 + sc;
    }
    __syncthreads();

    const int s = t / 64;        // wave = strip (0..8)
    const int l = t & 63;
    const int c = l & 15, g = l >> 4;

    // ---- QK^T : 9 tiles of 16x16, K=32 (one MFMA each) ----
    f32x4 acc[9];
    short8 aq = *(const short8*)(qlds + (16 * s + c) * 40 + 8 * g);
    #pragma unroll
    for (int kt = 0; kt < 9; kt++) {
        short8 bk = *(const short8*)(klds + (16 * kt + c) * 40 + 8 * g);
        f32x4 z = {0.f, 0.f, 0.f, 0.f};
        acc[kt] = __builtin_amdgcn_mfma_f32_16x16x32_bf16(aq, bk, z, 0, 0, 0);
    }

    // ---- bias + mask ----
    int eqr[4], cnr[4];
    #pragma unroll
    for (int r = 0; r < 4; r++) {
        int R = 16 * s + 4 * g + r;
        eqr[r] = eqa[R]; cnr[r] = cnta[R];
    }
    #pragma unroll
    for (int kt = 0; kt < 9; kt++) {
        int emc = ema[16 * kt + c], cnc = cnta[16 * kt + c];
        #pragma unroll
        for (int r = 0; r < 4; r++)
            acc[kt][r] += biaslds[eqr[r] + emc] + ((cnr[r] == cnc) ? 0.f : -100.f);
    }

    // ---- softmax over 144 cols (per row: 9 regs x 16 lanes of group) ----
    float mx[4] = {-1e30f, -1e30f, -1e30f, -1e30f};
    #pragma unroll
    for (int kt = 0; kt < 9; kt++)
        #pragma unroll
        for (int r = 0; r < 4; r++) mx[r] = fmaxf(mx[r], acc[kt][r]);
    #pragma unroll
    for (int r = 0; r < 4; r++) {
        mx[r] = fmaxf(mx[r], __shfl_xor(mx[r], 1));
        mx[r] = fmaxf(mx[r], __shfl_xor(mx[r], 2));
        mx[r] = fmaxf(mx[r], __shfl_xor(mx[r], 4));
        mx[r] = fmaxf(mx[r], __shfl_xor(mx[r], 8));
    }
    float sm[4] = {0.f, 0.f, 0.f, 0.f};
    #pragma unroll
    for (int kt = 0; kt < 9; kt++)
        #pragma unroll
        for (int r = 0; r < 4; r++) {
            float e = __expf(acc[kt][r] - mx[r]);
            acc[kt][r] = e; sm[r] += e;
        }
    #pragma unroll
    for (int r = 0; r < 4; r++) {
        sm[r] += __shfl_xor(sm[r], 1);
        sm[r] += __shfl_xor(sm[r], 2);
        sm[r] += __shfl_xor(sm[r], 4);
        sm[r] += __shfl_xor(sm[r], 8);
        sm[r] = 1.0f / sm[r];
    }

    // ---- PV : O[16 x 32] per wave, K = 144 padded to 160 ----
    unsigned short* ps = pscratch + s * 640;
    f32x4 oacc[2] = {{0.f,0.f,0.f,0.f}, {0.f,0.f,0.f,0.f}};
    for (int kc = 0; kc < 5; kc++) {
        #pragma unroll
        for (int tt = 0; tt < 2; tt++) {
            int kt = 2 * kc + tt;
            #pragma unroll
            for (int r = 0; r < 4; r++) {
                float pv = (kt < 9) ? acc[kt][r] * sm[r] : 0.f;
                ps[(4 * g + r) * 40 + tt * 16 + c] = f2b(pv);
            }
        }
        short8 ap = *(const short8*)(ps + c * 40 + 8 * g);
        #pragma unroll
        for (int dt = 0; dt < 2; dt++) {
            union { unsigned short e[8]; short8 v; } bv;
            #pragma unroll
            for (int j = 0; j < 8; j++)
                bv.e[j] = vlds[(kc * 32 + 8 * g + j) * 36 + dt * 16 + c];
            oacc[dt] = __builtin_amdgcn_mfma_f32_16x16x32_bf16(ap, bv.v, oacc[dt], 0, 0, 0);
        }
    }
    #pragma unroll
    for (int dt = 0; dt < 2; dt++)
        #pragma unroll
        for (int r = 0; r < 4; r++)
            ob[tb + (16 * s + 4 * g + r) * 32 + dt * 16 + c] = oacc[dt][r];
}

// ---------------------------------------------------------------------------
// Proj: rows = windowed tokens, A from tiled o, K=192, N=192 (full-N acc)
// writes xa[orig] = x[orig] + o@W + b   (inverse roll/partition scatter)
// ---------------------------------------------------------------------------
__global__ __launch_bounds__(256) void proj_kernel(
    const float* __restrict__ ot, const float* __restrict__ x,
    const float* __restrict__ w,  const float* __restrict__ pb,
    float* __restrict__ xa)
{
    __shared__ float As[64][68];
    __shared__ float Ws[64][196];
    __shared__ int s_ob[64], s_xb[64];

    const int t = threadIdx.x, m0 = blockIdx.x * 64;
    if (t < 64) {
        int row = m0 + t;
        int bl = row / 9216; int rem = row - bl * 9216;
        int wi = rem / 144;  int n = rem - wi * 144;
        s_ob[t] = bl * 1769472 + wi * 4608 + n * 32;
        s_xb[t] = src_off(row);
    }
    const int ty = t >> 4, tx = t & 15;
    const int r0 = ty * 4, c0 = tx * 4;
    float acc[3][4][4] = {};

    for (int kc = 0; kc < 3; kc++) {
        __syncthreads();
        for (int V = t; V < 1024; V += 256) {
            int r = V >> 4, kq = (V & 15) * 4;
            int k = kc * 64 + kq; int hh = k >> 5, d = k & 31;
            *(float4*)(&As[r][kq]) = *(const float4*)(ot + s_ob[r] + hh * 294912 + d);
        }
        for (int V = t; V < 3072; V += 256) {
            int kr = V / 48, c4 = (V - kr * 48) * 4;
            *(float4*)(&Ws[kr][c4]) = *(const float4*)(w + (kc * 64 + kr) * 192 + c4);
        }
        __syncthreads();
        for (int kk = 0; kk < 64; kk += 4) {
            float a[4][4];
            ld4(a[0], &As[r0 + 0][kk]); ld4(a[1], &As[r0 + 1][kk]);
            ld4(a[2], &As[r0 + 2][kk]); ld4(a[3], &As[r0 + 3][kk]);
            #pragma unroll
            for (int cc = 0; cc < 3; cc++)
                #pragma unroll
                for (int jk = 0; jk < 4; jk++) {
                    float b4[4]; ld4(b4, &Ws[kk + jk][cc * 64 + c0]);
                    #pragma unroll
                    for (int i = 0; i < 4; i++)
                        #pragma unroll
                        for (int j = 0; j < 4; j++)
                            acc[cc][i][j] += a[i][jk] * b4[j];
                }
        }
    }
    #pragma unroll
    for (int cc = 0; cc < 3; cc++) {
        int c = cc * 64 + c0;
        float b4[4]; ld4(b4, pb + c);
        #pragma unroll
        for (int i = 0; i < 4; i++) {
            int xb = s_xb[r0 + i] + c;
            float xv[4]; ld4(xv, x + xb);
            float o4[4];
            #pragma unroll
            for (int j = 0; j < 4; j++) o4[j] = acc[cc][i][j] + b4[j] + xv[j];
            st4(xa + xb, o4);
        }
    }
}

// ---------------------------------------------------------------------------
// LN2: 4 tokens per block (one wave each)
// ---------------------------------------------------------------------------
__global__ __launch_bounds__(256) void ln2_kernel(
    const float* __restrict__ xa, const float* __restrict__ w,
    const float* __restrict__ b,  float* __restrict__ y)
{
    int wv = threadIdx.x >> 6, ln = threadIdx.x & 63;
    int tok = blockIdx.x * 4 + wv;
    const float* xr = xa + tok * 192;
    float v0 = xr[ln], v1 = xr[ln + 64], v2 = xr[ln + 128];
    float s = v0 + v1 + v2, s2 = v0 * v0 + v1 * v1 + v2 * v2;
    #pragma unroll
    for (int off = 1; off < 64; off <<= 1) {
        s += __shfl_xor(s, off); s2 += __shfl_xor(s2, off);
    }
    float mu = s * (1.f / 192.f);
    float rs = 1.0f / sqrtf(s2 * (1.f / 192.f) - mu * mu + 1e-5f);
    float* yr = y + tok * 192;
    yr[ln]       = (v0 - mu) * rs * w[ln]       + b[ln];
    yr[ln + 64]  = (v1 - mu) * rs * w[ln + 64]  + b[ln + 64];
    yr[ln + 128] = (v2 - mu) * rs * w[ln + 128] + b[ln + 128];
}

// ---------------------------------------------------------------------------
// FC1 (+exact GELU): K=192, N=768, M-slice
// ---------------------------------------------------------------------------
__global__ __launch_bounds__(256) void fc1_kernel(
    const float* __restrict__ y, const float* __restrict__ w,
    const float* __restrict__ bias, float* __restrict__ tout, int slice_base)
{
    __shared__ float As[64][196];
    __shared__ float Ws[32][64];
    const int t = threadIdx.x, m0 = blockIdx.x * 64;

    for (int V = t; V < 3072; V += 256) {
        int r = V / 48, c4 = (V - (V / 48) * 48) * 4;
        *(float4*)(&As[r][c4]) = *(const float4*)(y + (slice_base + m0 + r) * 192 + c4);
    }
    __syncthreads();

    const int ty = t >> 4, tx = t & 15;
    const int r0 = ty * 4, c0 = tx * 4;

    for (int nc = 0; nc < 12; nc++) {
        float acc[4][4] = {};
        for (int kc = 0; kc < 6; kc++) {
            __syncthreads();
            {
                int kr = t >> 4, c4 = (t & 15) * 4;
                #pragma unroll
                for (int it = 0; it < 2; it++) {
                    int krr = kr + it * 16;
                    *(float4*)(&Ws[krr][c4]) =
                        *(const float4*)(w + (kc * 32 + krr) * 768 + nc * 64 + c4);
                }
            }
            __syncthreads();
            const int kb = kc * 32;
            #pragma unroll
            for (int kk = 0; kk < 32; kk += 4) {
                float a[4][4];
                ld4(a[0], &As[r0 + 0][kb + kk]);
                ld4(a[1], &As[r0 + 1][kb + kk]);
                ld4(a[2], &As[r0 + 2][kb + kk]);
                ld4(a[3], &As[r0 + 3][kb + kk]);
                #pragma unroll
                for (int jk = 0; jk < 4; jk++) {
                    float b4[4]; ld4(b4, &Ws[kk + jk][c0]);
                    #pragma unroll
                    for (int i = 0; i < 4; i++)
                        #pragma unroll
                        for (int j = 0; j < 4; j++)
                            acc[i][j] += a[i][jk] * b4[j];
                }
            }
        }
        int c = nc * 64 + c0;
        float b4[4]; ld4(b4, bias + c);
        #pragma unroll
        for (int i = 0; i < 4; i++) {
            int row = m0 + r0 + i;
            float o4[4];
            #pragma unroll
            for (int j = 0; j < 4; j++) o4[j] = gelu_exact(acc[i][j] + b4[j]);
            st4(tout + row * 768 + c, o4);
        }
    }
}

// ---------------------------------------------------------------------------
// FC2 + residual: K=768, N=192 (full-N acc), M-slice
// ---------------------------------------------------------------------------
__global__ __launch_bounds__(256) void fc2_kernel(
    const float* __restrict__ tin, const float* __restrict__ xa,
    const float* __restrict__ w,   const float* __restrict__ fb,
    float* __restrict__ out, int slice_base)
{
    __shared__ float As[64][68];
    __shared__ float Ws[64][196];
    const int t = threadIdx.x, m0 = blockIdx.x * 64;
    const int ty = t >> 4, tx = t & 15;
    const int r0 = ty * 4, c0 = tx * 4;
    float acc[3][4][4] = {};

    for (int kc = 0; kc < 12; kc++) {
        __syncthreads();
        for (int V = t; V < 1024; V += 256) {
            int r = V >> 4, kq = (V & 15) * 4;
            *(float4*)(&As[r][kq]) = *(const float4*)(tin + (m0 + r) * 768 + kc * 64 + kq);
        }
        for (int V = t; V < 3072; V += 256) {
            int kr = V / 48, c4 = (V - kr * 48) * 4;
            *(float4*)(&Ws[kr][c4]) = *(const float4*)(w + (kc * 64 + kr) * 192 + c4);
        }
        __syncthreads();
        for (int kk = 0; kk < 64; kk += 4) {
            float a[4][4];
            ld4(a[0], &As[r0 + 0][kk]); ld4(a[1], &As[r0 + 1][kk]);
            ld4(a[2], &As[r0 + 2][kk]); ld4(a[3], &As[r0 + 3][kk]);
            #pragma unroll
            for (int cc = 0; cc < 3; cc++)
                #pragma unroll
                for (int jk = 0; jk < 4; jk++) {
                    float b4[4]; ld4(b4, &Ws[kk + jk][cc * 64 + c0]);
                    #pragma unroll
                    for (int i = 0; i < 4; i++)
                        #pragma unroll
                        for (int j = 0; j < 4; j++)
                            acc[cc][i][j] += a[i][jk] * b4[j];
                }
        }
    }
    #pragma unroll
    for (int cc = 0; cc < 3; cc++) {
        int c = cc * 64 + c0;
        float b4[4]; ld4(b4, fb + c);
        #pragma unroll
        for (int i = 0; i < 4; i++) {
            int row = slice_base + m0 + r0 + i;
            int off = row * 192 + c;
            float xv[4]; ld4(xv, xa + off);
            float o4[4];
            #pragma unroll
            for (int j = 0; j < 4; j++) o4[j] = acc[cc][i][j] + b4[j] + xv[j];
            st4(out + off, o4);
        }
    }
}

// ---------------------------------------------------------------------------
extern "C" void kernel_launch(void* const* d_in, const int* in_sizes, int n_in,
                              void* d_out, int out_size, void* d_ws, size_t ws_size,
                              hipStream_t stream)
{
    const float* x      = (const float*)d_in[0];
    const float* ln1w   = (const float*)d_in[1];
    const float* ln1b   = (const float*)d_in[2];
    const float* qkvw   = (const float*)d_in[3];
    const float* qkvb   = (const float*)d_in[4];
    const float* projw  = (const float*)d_in[5];
    const float* projb  = (const float*)d_in[6];
    const float* biast  = (const float*)d_in[7];
    const float* ln2w   = (const float*)d_in[8];
    const float* ln2b   = (const float*)d_in[9];
    const float* fc1w   = (const float*)d_in[10];
    const float* fc1b   = (const float*)d_in[11];
    const float* fc2w   = (const float*)d_in[12];
    const float* fc2b   = (const float*)d_in[13];
    float* out = (float*)d_out;

    // Workspace: 2 slots of 138240*192 floats (212 MB). Third buffer aliases
    // d_out (v -> y), safe under strictly sequential kernel ordering.
    const size_t SLOT = 26542080;       // 138240*192 floats
    float* qbuf = (float*)d_ws;         // q -> o (in-place) -> fc1 intermediate
    float* kbuf = qbuf + SLOT;          // k -> xa (x + attn residual)
    float* vbuf = out;                  // v -> y (LN2 out) -> final out

    qkv_ln_kernel<<<2160, 256, 0, stream>>>(x, ln1w, ln1b, qkvw, qkvb, qbuf, kbuf, vbuf);
    attn_kernel<<<5760, 576, 0, stream>>>(qbuf, kbuf, vbuf, biast, qbuf);
    proj_kernel<<<2160, 256, 0, stream>>>(qbuf, x, projw, projb, kbuf);
    ln2_kernel<<<34560, 256, 0, stream>>>(kbuf, ln2w, ln2b, vbuf);
    for (int s = 0; s < 4; s++) {
        fc1_kernel<<<540, 256, 0, stream>>>(vbuf, fc1w, fc1b, qbuf, s * 34560);
        fc2_kernel<<<540, 256, 0, stream>>>(qbuf, kbuf, fc2w, fc2b, out, s * 34560);
    }
}

// Round 4
// 1611.033 us; speedup vs baseline: 2.4577x; 2.0220x over previous
//
#include <hip/hip_runtime.h>
#include <math.h>

#define DI __device__ __forceinline__

// PL=8 LAT=96 LON=180 C=192 H=6 D=32 ; windows (2,6,12) shift (1,3,6)
// NPL=4 NLAT=16 NLON=15 NW=64 N=144 L=138240 ; BIAS_SIZE=3444
constexpr float QSCALE = 0.17677669529663687f; // 32^-0.5

typedef unsigned short bf16_t;
typedef __attribute__((ext_vector_type(8))) short short8;
typedef __attribute__((ext_vector_type(4))) float f32x4;

DI unsigned short f2b(float f) {            // fp32 -> bf16 bits, RNE
    unsigned u = __builtin_bit_cast(unsigned, f);
    return (unsigned short)((u + 0x7FFFu + ((u >> 16) & 1u)) >> 16);
}

// windowed row -> original token offset (*192), applying forward roll (-1,-3,-6)
DI int src_off(int row) {
    int bl  = row / 9216;  int rem = row - bl * 9216;   // 9216 = 64*144
    int wi  = rem / 144;   int n   = rem - wi * 144;
    int npl = wi >> 4,     nlat = wi & 15;
    int w0  = n / 72;      int rn = n - w0 * 72;
    int w1  = rn / 12;     int w2 = rn - w1 * 12;
    int pl = npl * 2 + w0 + 1;  if (pl >= 8)   pl -= 8;
    int la = nlat * 6 + w1 + 3; if (la >= 96)  la -= 96;
    int lo = bl * 12 + w2 + 6;  if (lo >= 180) lo -= 180;
    return ((pl * 96 + la) * 180 + lo) * 192;
}

DI int tiled_base(int row) {   // windowed row -> q/k/v tiled base (h,d added later)
    int bl = row / 9216; int rem = row - bl * 9216;
    int wi = rem / 144;  int n = rem - wi * 144;
    return bl * 1769472 + wi * 4608 + n * 32;
}

DI float gelu_exact(float v) {
    return 0.5f * v * (1.0f + erff(v * 0.70710678118654752440f));
}

// ---------------------------------------------------------------------------
// Weight transpose + bf16 convert: src fp32 [K][N] -> dst bf16 [N][K]
// ---------------------------------------------------------------------------
__global__ __launch_bounds__(256) void wconv_kernel(
    const float* __restrict__ src, bf16_t* __restrict__ dst, int K, int N)
{
    int i = blockIdx.x * 256 + threadIdx.x;
    if (i < K * N) {
        int n = i / K, k = i - n * K;
        dst[i] = f2b(src[k * N + n]);
    }
}

// ---------------------------------------------------------------------------
// QKV via MFMA: LN1 fused into bf16 A-staging. K=192, N=576.
// Block=256thr(4 waves), M-tile 64. B-frags straight from global W^T (L1-hot).
// Outputs q/k/v bf16 in tiled [bl][h][w][n][d] layout; q scaled.
// ---------------------------------------------------------------------------
__global__ __launch_bounds__(256) void qkv_mfma_kernel(
    const float* __restrict__ x,
    const float* __restrict__ ln1w, const float* __restrict__ ln1b,
    const bf16_t* __restrict__ wt,   // [576][192] bf16
    const float* __restrict__ bias,  // [576]
    bf16_t* __restrict__ qo, bf16_t* __restrict__ ko, bf16_t* __restrict__ vo)
{
    __shared__ bf16_t Alds[64 * 200];
    __shared__ float lw[192], lb[192], sbias[576];
    __shared__ float s_mu[64], s_rs[64];
    __shared__ int   s_src[64], s_rb[64];

    const int t  = threadIdx.x;
    const int m0 = blockIdx.x * 64;

    if (t < 192) { lw[t] = ln1w[t]; lb[t] = ln1b[t]; }
    for (int v = t; v < 576; v += 256) sbias[v] = bias[v];
    if (t < 64) {
        s_src[t] = src_off(m0 + t);
        s_rb[t]  = tiled_base(m0 + t);
    }
    __syncthreads();

    // per-row LN stats: 4 threads per row
    {
        int r = t >> 2, p = t & 3;
        const float* xr = x + s_src[r] + p * 48;
        float s = 0.f, s2 = 0.f;
        #pragma unroll
        for (int i = 0; i < 12; i++) {
            float4 v = *(const float4*)(xr + i * 4);
            s  += v.x + v.y + v.z + v.w;
            s2 += v.x*v.x + v.y*v.y + v.z*v.z + v.w*v.w;
        }
        s  += __shfl_xor(s, 1);  s  += __shfl_xor(s, 2);
        s2 += __shfl_xor(s2, 1); s2 += __shfl_xor(s2, 2);
        if (p == 0) {
            float mu  = s * (1.f / 192.f);
            float var = s2 * (1.f / 192.f) - mu * mu;
            s_mu[r] = mu;
            s_rs[r] = 1.0f / sqrtf(var + 1e-5f);
        }
    }
    __syncthreads();

    // stage LN'd A tile as bf16
    for (int V = t; V < 3072; V += 256) {
        int r = V / 48, c4 = (V - (V / 48) * 48) * 4;
        float4 a = *(const float4*)(x + s_src[r] + c4);
        float mu = s_mu[r], rs = s_rs[r];
        ushort4 o;
        o.x = f2b((a.x - mu) * rs * lw[c4 + 0] + lb[c4 + 0]);
        o.y = f2b((a.y - mu) * rs * lw[c4 + 1] + lb[c4 + 1]);
        o.z = f2b((a.z - mu) * rs * lw[c4 + 2] + lb[c4 + 2]);
        o.w = f2b((a.w - mu) * rs * lw[c4 + 3] + lb[c4 + 3]);
        *(ushort4*)(&Alds[r * 200 + c4]) = o;
    }
    __syncthreads();

    const int l = t & 63, s = t >> 6;    // wave s owns rows 16s..16s+15
    const int c = l & 15, g = l >> 4;
    const bf16_t* arow = Alds + (16 * s + c) * 200;

    for (int nc = 0; nc < 9; nc++) {
        f32x4 acc[4] = {};
        #pragma unroll
        for (int kc = 0; kc < 6; kc++) {
            short8 a = *(const short8*)(arow + kc * 32 + 8 * g);
            #pragma unroll
            for (int ct = 0; ct < 4; ct++) {
                short8 b = *(const short8*)(wt + (nc * 64 + ct * 16 + c) * 192 + kc * 32 + 8 * g);
                acc[ct] = __builtin_amdgcn_mfma_f32_16x16x32_bf16(a, b, acc[ct], 0, 0, 0);
            }
        }
        #pragma unroll
        for (int ct = 0; ct < 4; ct++) {
            int col = nc * 64 + ct * 16 + c;
            int buf = col / 192, cc = col - buf * 192;
            int h = cc >> 5, d = cc & 31;
            bf16_t* outp = (buf == 0) ? qo : ((buf == 1) ? ko : vo);
            float sc = (buf == 0) ? QSCALE : 1.0f;
            float bv = sbias[col];
            #pragma unroll
            for (int r = 0; r < 4; r++) {
                int row = 16 * s + 4 * g + r;
                outp[s_rb[row] + h * 294912 + d] = f2b((acc[ct][r] + bv) * sc);
            }
        }
    }
}

// ---------------------------------------------------------------------------
// Attention via MFMA bf16 (unchanged structure, bf16 I/O): 9 waves per (bl,h,w).
// ---------------------------------------------------------------------------
__global__ __launch_bounds__(576, 5) void attn_kernel(
    const bf16_t* __restrict__ qb, const bf16_t* __restrict__ kb,
    const bf16_t* __restrict__ vb, const float* __restrict__ bt,
    bf16_t* __restrict__ ob)
{
    __shared__ bf16_t qlds[144 * 40];
    __shared__ bf16_t klds[144 * 40];
    __shared__ bf16_t vlds[160 * 36];           // rows 144..159 zero
    __shared__ float biaslds[3444];             // bt[:, wi, h]
    __shared__ int eqa[144], ema[144], cnta[144];
    __shared__ bf16_t pscratch[9 * 640];        // per-wave 16 x 40

    const int t   = threadIdx.x;
    const int bid = blockIdx.x;              // ((bl*6 + h)*64 + w)
    const int wi  = bid & 63;
    const int bh  = bid >> 6;
    const int h   = bh % 6;
    const int bl  = bh / 6;
    const int tb  = bid * 4608;
    const int wh  = wi * 6 + h;

    for (int idx = t; idx < 1152; idx += 576) {
        int r = idx >> 3, q4 = (idx & 7) * 4;
        *(ushort4*)(&qlds[r * 40 + q4]) = *(const ushort4*)(qb + tb + r * 32 + q4);
        *(ushort4*)(&klds[r * 40 + q4]) = *(const ushort4*)(kb + tb + r * 32 + q4);
        *(ushort4*)(&vlds[r * 36 + q4]) = *(const ushort4*)(vb + tb + r * 32 + q4);
    }
    vlds[144 * 36 + t] = 0;                      // 16*36 = 576 pad elems
    for (int e = t; e < 3444; e += 576) biaslds[e] = bt[e * 384 + wh];
    if (t < 144) {
        int n = t;
        int w0 = n / 72; int rn = n - w0 * 72;
        int w1 = rn / 12; int w2 = rn - w1 * 12;
        eqa[t] = 828 * w0 + 23 * w1 + w2;
        ema[t] = 1656 * w0 + 138 * w1 + 12 * w2 + 11;
        int npl = wi >> 4, nlat = wi & 15;
        int p0 = npl * 2 + w0, p1 = nlat * 6 + w1, p2 = bl * 12 + w2;
        int sa = (p0 < 6) ? 0 : ((p0 < 7) ? 1 : 2);
        int sb = (p1 < 90) ? 0 : ((p1 < 93) ? 1 : 2);
        int sc = (p2 < 174) ? 0 : 1;
        cnta[t] = sa * 9 + sb * 3 + sc;
    }
    __syncthreads();

    const int s = t / 64;        // wave = strip (0..8)
    const int l = t & 63;
    const int c = l & 15, g = l >> 4;

    // ---- QK^T ----
    f32x4 acc[9];
    short8 aq = *(const short8*)(qlds + (16 * s + c) * 40 + 8 * g);
    #pragma unroll
    for (int kt = 0; kt < 9; kt++) {
        short8 bk = *(const short8*)(klds + (16 * kt + c) * 40 + 8 * g);
        f32x4 z = {0.f, 0.f, 0.f, 0.f};
        acc[kt] = __builtin_amdgcn_mfma_f32_16x16x32_bf16(aq, bk, z, 0, 0, 0);
    }

    // ---- bias + mask ----
    int eqr[4], cnr[4];
    #pragma unroll
    for (int r = 0; r < 4; r++) {
        int R = 16 * s + 4 * g + r;
        eqr[r] = eqa[R]; cnr[r] = cnta[R];
    }
    #pragma unroll
    for (int kt = 0; kt < 9; kt++) {
        int emc = ema[16 * kt + c], cnc = cnta[16 * kt + c];
        #pragma unroll
        for (int r = 0; r < 4; r++)
            acc[kt][r] += biaslds[eqr[r] + emc] + ((cnr[r] == cnc) ? 0.f : -100.f);
    }

    // ---- softmax over 144 cols ----
    float mx[4] = {-1e30f, -1e30f, -1e30f, -1e30f};
    #pragma unroll
    for (int kt = 0; kt < 9; kt++)
        #pragma unroll
        for (int r = 0; r < 4; r++) mx[r] = fmaxf(mx[r], acc[kt][r]);
    #pragma unroll
    for (int r = 0; r < 4; r++) {
        mx[r] = fmaxf(mx[r], __shfl_xor(mx[r], 1));
        mx[r] = fmaxf(mx[r], __shfl_xor(mx[r], 2));
        mx[r] = fmaxf(mx[r], __shfl_xor(mx[r], 4));
        mx[r] = fmaxf(mx[r], __shfl_xor(mx[r], 8));
    }
    float sm[4] = {0.f, 0.f, 0.f, 0.f};
    #pragma unroll
    for (int kt = 0; kt < 9; kt++)
        #pragma unroll
        for (int r = 0; r < 4; r++) {
            float e = __expf(acc[kt][r] - mx[r]);
            acc[kt][r] = e; sm[r] += e;
        }
    #pragma unroll
    for (int r = 0; r < 4; r++) {
        sm[r] += __shfl_xor(sm[r], 1);
        sm[r] += __shfl_xor(sm[r], 2);
        sm[r] += __shfl_xor(sm[r], 4);
        sm[r] += __shfl_xor(sm[r], 8);
        sm[r] = 1.0f / sm[r];
    }

    // ---- PV : O[16 x 32] per wave, K padded to 160 ----
    bf16_t* ps = pscratch + s * 640;
    f32x4 oacc[2] = {{0.f,0.f,0.f,0.f}, {0.f,0.f,0.f,0.f}};
    for (int kc = 0; kc < 5; kc++) {
        #pragma unroll
        for (int tt = 0; tt < 2; tt++) {
            int kt = 2 * kc + tt;
            #pragma unroll
            for (int r = 0; r < 4; r++) {
                float pv = (kt < 9) ? acc[kt][r] * sm[r] : 0.f;
                ps[(4 * g + r) * 40 + tt * 16 + c] = f2b(pv);
            }
        }
        short8 ap = *(const short8*)(ps + c * 40 + 8 * g);
        #pragma unroll
        for (int dt = 0; dt < 2; dt++) {
            union { bf16_t e[8]; short8 v; } bv;
            #pragma unroll
            for (int j = 0; j < 8; j++)
                bv.e[j] = vlds[(kc * 32 + 8 * g + j) * 36 + dt * 16 + c];
            oacc[dt] = __builtin_amdgcn_mfma_f32_16x16x32_bf16(ap, bv.v, oacc[dt], 0, 0, 0);
        }
    }
    #pragma unroll
    for (int dt = 0; dt < 2; dt++)
        #pragma unroll
        for (int r = 0; r < 4; r++)
            ob[tb + (16 * s + 4 * g + r) * 32 + dt * 16 + c] = f2b(oacc[dt][r]);
}

// ---------------------------------------------------------------------------
// Proj via MFMA: A = o bf16 (tiled gather), K=192, N=192.
// Epilogue: xa[orig] = x[orig] + oW + b   (fp32, written to d_out)
// ---------------------------------------------------------------------------
__global__ __launch_bounds__(256) void proj_mfma_kernel(
    const bf16_t* __restrict__ ot, const float* __restrict__ x,
    const bf16_t* __restrict__ wt,  // [192][192] bf16
    const float* __restrict__ pb,
    float* __restrict__ xa)
{
    __shared__ bf16_t Alds[64 * 200];
    __shared__ float sbias[192];
    __shared__ int s_ob[64], s_xb[64];

    const int t = threadIdx.x, m0 = blockIdx.x * 64;
    if (t < 192) sbias[t] = pb[t];
    if (t < 64) {
        s_ob[t] = tiled_base(m0 + t);
        s_xb[t] = src_off(m0 + t);
    }
    __syncthreads();

    for (int V = t; V < 3072; V += 256) {
        int r = V / 48, c4 = (V - (V / 48) * 48) * 4;
        int h = c4 >> 5, d = c4 & 31;
        *(ushort4*)(&Alds[r * 200 + c4]) = *(const ushort4*)(ot + s_ob[r] + h * 294912 + d);
    }
    __syncthreads();

    const int l = t & 63, s = t >> 6;
    const int c = l & 15, g = l >> 4;
    const bf16_t* arow = Alds + (16 * s + c) * 200;

    for (int nc = 0; nc < 3; nc++) {
        f32x4 acc[4] = {};
        #pragma unroll
        for (int kc = 0; kc < 6; kc++) {
            short8 a = *(const short8*)(arow + kc * 32 + 8 * g);
            #pragma unroll
            for (int ct = 0; ct < 4; ct++) {
                short8 b = *(const short8*)(wt + (nc * 64 + ct * 16 + c) * 192 + kc * 32 + 8 * g);
                acc[ct] = __builtin_amdgcn_mfma_f32_16x16x32_bf16(a, b, acc[ct], 0, 0, 0);
            }
        }
        #pragma unroll
        for (int ct = 0; ct < 4; ct++) {
            int col = nc * 64 + ct * 16 + c;
            float bv = sbias[col];
            #pragma unroll
            for (int r = 0; r < 4; r++) {
                int row = 16 * s + 4 * g + r;
                int off = s_xb[row] + col;
                xa[off] = acc[ct][r] + bv + x[off];
            }
        }
    }
}

// ---------------------------------------------------------------------------
// LN2: reads xa fp32 (d_out), writes y bf16
// ---------------------------------------------------------------------------
__global__ __launch_bounds__(256) void ln2_kernel(
    const float* __restrict__ xa, const float* __restrict__ w,
    const float* __restrict__ b,  bf16_t* __restrict__ y)
{
    int wv = threadIdx.x >> 6, ln = threadIdx.x & 63;
    int tok = blockIdx.x * 4 + wv;
    const float* xr = xa + tok * 192;
    float v0 = xr[ln], v1 = xr[ln + 64], v2 = xr[ln + 128];
    float s = v0 + v1 + v2, s2 = v0 * v0 + v1 * v1 + v2 * v2;
    #pragma unroll
    for (int off = 1; off < 64; off <<= 1) {
        s += __shfl_xor(s, off); s2 += __shfl_xor(s2, off);
    }
    float mu = s * (1.f / 192.f);
    float rs = 1.0f / sqrtf(s2 * (1.f / 192.f) - mu * mu + 1e-5f);
    bf16_t* yr = y + tok * 192;
    yr[ln]       = f2b((v0 - mu) * rs * w[ln]       + b[ln]);
    yr[ln + 64]  = f2b((v1 - mu) * rs * w[ln + 64]  + b[ln + 64]);
    yr[ln + 128] = f2b((v2 - mu) * rs * w[ln + 128] + b[ln + 128]);
}

// ---------------------------------------------------------------------------
// FC1 via MFMA (+exact GELU): K=192, N=768, M-slice. y bf16 -> t bf16.
// ---------------------------------------------------------------------------
__global__ __launch_bounds__(256) void fc1_mfma_kernel(
    const bf16_t* __restrict__ y, const bf16_t* __restrict__ wt,  // [768][192]
    const float* __restrict__ bias, bf16_t* __restrict__ tout, int slice_base)
{
    __shared__ bf16_t Alds[64 * 200];
    __shared__ float sbias[768];

    const int t = threadIdx.x, m0 = blockIdx.x * 64;
    for (int v = t; v < 768; v += 256) sbias[v] = bias[v];
    for (int V = t; V < 3072; V += 256) {
        int r = V / 48, c4 = (V - (V / 48) * 48) * 4;
        *(ushort4*)(&Alds[r * 200 + c4]) =
            *(const ushort4*)(y + (slice_base + m0 + r) * 192 + c4);
    }
    __syncthreads();

    const int l = t & 63, s = t >> 6;
    const int c = l & 15, g = l >> 4;
    const bf16_t* arow = Alds + (16 * s + c) * 200;

    for (int nc = 0; nc < 12; nc++) {
        f32x4 acc[4] = {};
        #pragma unroll
        for (int kc = 0; kc < 6; kc++) {
            short8 a = *(const short8*)(arow + kc * 32 + 8 * g);
            #pragma unroll
            for (int ct = 0; ct < 4; ct++) {
                short8 b = *(const short8*)(wt + (nc * 64 + ct * 16 + c) * 192 + kc * 32 + 8 * g);
                acc[ct] = __builtin_amdgcn_mfma_f32_16x16x32_bf16(a, b, acc[ct], 0, 0, 0);
            }
        }
        #pragma unroll
        for (int ct = 0; ct < 4; ct++) {
            int col = nc * 64 + ct * 16 + c;
            float bv = sbias[col];
            #pragma unroll
            for (int r = 0; r < 4; r++) {
                int row = m0 + 16 * s + 4 * g + r;     // slice-local
                tout[row * 768 + col] = f2b(gelu_exact(acc[ct][r] + bv));
            }
        }
    }
}

// ---------------------------------------------------------------------------
// FC2 via MFMA + residual: K=768, N=192. t bf16 -> out fp32 (in-place over xa).
// ---------------------------------------------------------------------------
__global__ __launch_bounds__(256) void fc2_mfma_kernel(
    const bf16_t* __restrict__ tin, const bf16_t* __restrict__ wt,  // [192][768]
    const float* __restrict__ fb, float* out, int slice_base)
{
    __shared__ bf16_t Alds[64 * 72];
    __shared__ float sbias[192];

    const int t = threadIdx.x, m0 = blockIdx.x * 64;
    if (t < 192) sbias[t] = fb[t];

    const int l = t & 63, s = t >> 6;
    const int c = l & 15, g = l >> 4;

    f32x4 acc[12] = {};
    for (int kc = 0; kc < 12; kc++) {        // 64-wide K chunks
        __syncthreads();
        for (int V = t; V < 1024; V += 256) {
            int r = V >> 4, k4 = (V & 15) * 4;
            *(ushort4*)(&Alds[r * 72 + k4]) =
                *(const ushort4*)(tin + (m0 + r) * 768 + kc * 64 + k4);
        }
        __syncthreads();
        #pragma unroll
        for (int kh = 0; kh < 2; kh++) {
            short8 a = *(const short8*)(Alds + (16 * s + c) * 72 + kh * 32 + 8 * g);
            #pragma unroll
            for (int ct = 0; ct < 12; ct++) {
                short8 b = *(const short8*)(wt + (ct * 16 + c) * 768 + kc * 64 + kh * 32 + 8 * g);
                acc[ct] = __builtin_amdgcn_mfma_f32_16x16x32_bf16(a, b, acc[ct], 0, 0, 0);
            }
        }
    }
    #pragma unroll
    for (int ct = 0; ct < 12; ct++) {
        int col = ct * 16 + c;
        float bv = sbias[col];
        #pragma unroll
        for (int r = 0; r < 4; r++) {
            int row = slice_base + m0 + 16 * s + 4 * g + r;
            int off = row * 192 + col;
            out[off] = acc[ct][r] + bv + out[off];   // out holds xa
        }
    }
}

// ---------------------------------------------------------------------------
extern "C" void kernel_launch(void* const* d_in, const int* in_sizes, int n_in,
                              void* d_out, int out_size, void* d_ws, size_t ws_size,
                              hipStream_t stream)
{
    const float* x      = (const float*)d_in[0];
    const float* ln1w   = (const float*)d_in[1];
    const float* ln1b   = (const float*)d_in[2];
    const float* qkvw   = (const float*)d_in[3];
    const float* qkvb   = (const float*)d_in[4];
    const float* projw  = (const float*)d_in[5];
    const float* projb  = (const float*)d_in[6];
    const float* biast  = (const float*)d_in[7];
    const float* ln2w   = (const float*)d_in[8];
    const float* ln2b   = (const float*)d_in[9];
    const float* fc1w   = (const float*)d_in[10];
    const float* fc1b   = (const float*)d_in[11];
    const float* fc2w   = (const float*)d_in[12];
    const float* fc2b   = (const float*)d_in[13];
    float* out = (float*)d_out;

    // ws layout (bytes): 3 bf16 slots of 53,084,160 + transposed weights.
    //   R0: q -> o            R1: k -> y            R2: v -> t-slice
    //   xa lives in d_out (proj fully writes it; fc2 reads+writes in place).
    const size_t SLOTB = 53084160;   // 138240*192 bf16
    char* base = (char*)d_ws;
    bf16_t* qbuf = (bf16_t*)(base);
    bf16_t* kbuf = (bf16_t*)(base + SLOTB);
    bf16_t* vbuf = (bf16_t*)(base + 2 * SLOTB);
    bf16_t* wtq  = (bf16_t*)(base + 3 * SLOTB);   // [576][192]
    bf16_t* wtp  = wtq  + 110592;                 // [192][192]
    bf16_t* wtf1 = wtp  + 36864;                  // [768][192]
    bf16_t* wtf2 = wtf1 + 147456;                 // [192][768]

    wconv_kernel<<<432, 256, 0, stream>>>(qkvw, wtq, 192, 576);
    wconv_kernel<<<144, 256, 0, stream>>>(projw, wtp, 192, 192);
    wconv_kernel<<<576, 256, 0, stream>>>(fc1w, wtf1, 192, 768);
    wconv_kernel<<<576, 256, 0, stream>>>(fc2w, wtf2, 768, 192);

    qkv_mfma_kernel<<<2160, 256, 0, stream>>>(x, ln1w, ln1b, wtq, qkvb, qbuf, kbuf, vbuf);
    attn_kernel<<<5760, 576, 0, stream>>>(qbuf, kbuf, vbuf, biast, qbuf);
    proj_mfma_kernel<<<2160, 256, 0, stream>>>(qbuf, x, wtp, projb, out);
    ln2_kernel<<<34560, 256, 0, stream>>>(out, ln2w, ln2b, kbuf);
    for (int s = 0; s < 4; s++) {
        fc1_mfma_kernel<<<540, 256, 0, stream>>>(kbuf, wtf1, fc1b, vbuf, s * 34560);
        fc2_mfma_kernel<<<540, 256, 0, stream>>>(vbuf, wtf2, fc2b, out, s * 34560);
    }
}

// Round 5
// 1155.116 us; speedup vs baseline: 3.4278x; 1.3947x over previous
//
#include <hip/hip_runtime.h>
#include <math.h>

#define DI __device__ __forceinline__

// PL=8 LAT=96 LON=180 C=192 H=6 D=32 ; windows (2,6,12) shift (1,3,6)
// NPL=4 NLAT=16 NLON=15 NW=64 N=144 L=138240 ; BIAS_SIZE=3444
constexpr float QSCALE = 0.17677669529663687f; // 32^-0.5

typedef unsigned short bf16_t;
typedef __attribute__((ext_vector_type(8))) short short8;
typedef __attribute__((ext_vector_type(4))) float f32x4;

DI unsigned short f2b(float f) {            // fp32 -> bf16 bits, RNE
    unsigned u = __builtin_bit_cast(unsigned, f);
    return (unsigned short)((u + 0x7FFFu + ((u >> 16) & 1u)) >> 16);
}

// windowed row -> original token offset (*192), applying forward roll (-1,-3,-6)
DI int src_off(int row) {
    int bl  = row / 9216;  int rem = row - bl * 9216;   // 9216 = 64*144
    int wi  = rem / 144;   int n   = rem - wi * 144;
    int npl = wi >> 4,     nlat = wi & 15;
    int w0  = n / 72;      int rn = n - w0 * 72;
    int w1  = rn / 12;     int w2 = rn - w1 * 12;
    int pl = npl * 2 + w0 + 1;  if (pl >= 8)   pl -= 8;
    int la = nlat * 6 + w1 + 3; if (la >= 96)  la -= 96;
    int lo = bl * 12 + w2 + 6;  if (lo >= 180) lo -= 180;
    return ((pl * 96 + la) * 180 + lo) * 192;
}

DI int tiled_base(int row) {   // windowed row -> q/k/v tiled base (h,d added later)
    int bl = row / 9216; int rem = row - bl * 9216;
    int wi = rem / 144;  int n = rem - wi * 144;
    return bl * 1769472 + wi * 4608 + n * 32;
}

DI float gelu_exact(float v) {
    return 0.5f * v * (1.0f + erff(v * 0.70710678118654752440f));
}

// ---------------------------------------------------------------------------
// Weight transpose + bf16 convert: src fp32 [K][N] -> dst bf16 [N][K]
// ---------------------------------------------------------------------------
__global__ __launch_bounds__(256) void wconv_kernel(
    const float* __restrict__ src, bf16_t* __restrict__ dst, int K, int N)
{
    int i = blockIdx.x * 256 + threadIdx.x;
    if (i < K * N) {
        int n = i / K, k = i - n * K;
        dst[i] = f2b(src[k * N + n]);
    }
}

// ---------------------------------------------------------------------------
// QKV via MFMA: LN1 fused. K=192, N=576. 128 thr (2 waves), M-tile 64,
// wave owns 32 rows; acc[2][4] per nc chunk (B reused 2x, A 4x).
// ---------------------------------------------------------------------------
__global__ __launch_bounds__(128) void qkv_mfma_kernel(
    const float* __restrict__ x,
    const float* __restrict__ ln1w, const float* __restrict__ ln1b,
    const bf16_t* __restrict__ wt,   // [576][192] bf16
    const float* __restrict__ bias,  // [576]
    bf16_t* __restrict__ qo, bf16_t* __restrict__ ko, bf16_t* __restrict__ vo)
{
    __shared__ bf16_t Alds[64 * 200];
    __shared__ float lw[192], lb[192], sbias[576];
    __shared__ float s_mu[64], s_rs[64];
    __shared__ int   s_src[64], s_rb[64];

    const int t  = threadIdx.x;
    const int m0 = blockIdx.x * 64;

    for (int v = t; v < 192; v += 128) { lw[v] = ln1w[v]; lb[v] = ln1b[v]; }
    for (int v = t; v < 576; v += 128) sbias[v] = bias[v];
    if (t < 64) {
        s_src[t] = src_off(m0 + t);
        s_rb[t]  = tiled_base(m0 + t);
    }
    __syncthreads();

    // per-row LN stats: 2 threads per row
    {
        int r = t >> 1, p = t & 1;
        const float* xr = x + s_src[r] + p * 96;
        float s = 0.f, s2 = 0.f;
        #pragma unroll
        for (int i = 0; i < 24; i++) {
            float4 v = *(const float4*)(xr + i * 4);
            s  += v.x + v.y + v.z + v.w;
            s2 += v.x*v.x + v.y*v.y + v.z*v.z + v.w*v.w;
        }
        s  += __shfl_xor(s, 1);
        s2 += __shfl_xor(s2, 1);
        if (p == 0) {
            float mu  = s * (1.f / 192.f);
            float var = s2 * (1.f / 192.f) - mu * mu;
            s_mu[r] = mu;
            s_rs[r] = 1.0f / sqrtf(var + 1e-5f);
        }
    }
    __syncthreads();

    for (int V = t; V < 3072; V += 128) {
        int r = V / 48, c4 = (V - (V / 48) * 48) * 4;
        float4 a = *(const float4*)(x + s_src[r] + c4);
        float mu = s_mu[r], rs = s_rs[r];
        ushort4 o;
        o.x = f2b((a.x - mu) * rs * lw[c4 + 0] + lb[c4 + 0]);
        o.y = f2b((a.y - mu) * rs * lw[c4 + 1] + lb[c4 + 1]);
        o.z = f2b((a.z - mu) * rs * lw[c4 + 2] + lb[c4 + 2]);
        o.w = f2b((a.w - mu) * rs * lw[c4 + 3] + lb[c4 + 3]);
        *(ushort4*)(&Alds[r * 200 + c4]) = o;
    }
    __syncthreads();

    const int l = t & 63, s = t >> 6;    // wave s owns rows 32s..32s+31
    const int c = l & 15, g = l >> 4;
    const bf16_t* arow0 = Alds + (32 * s + c) * 200;
    const bf16_t* arow1 = arow0 + 16 * 200;

    for (int nc = 0; nc < 9; nc++) {
        f32x4 acc[2][4] = {};
        #pragma unroll
        for (int kc = 0; kc < 6; kc++) {
            short8 a0 = *(const short8*)(arow0 + kc * 32 + 8 * g);
            short8 a1 = *(const short8*)(arow1 + kc * 32 + 8 * g);
            #pragma unroll
            for (int ct = 0; ct < 4; ct++) {
                short8 b = *(const short8*)(wt + (nc * 64 + ct * 16 + c) * 192 + kc * 32 + 8 * g);
                acc[0][ct] = __builtin_amdgcn_mfma_f32_16x16x32_bf16(a0, b, acc[0][ct], 0, 0, 0);
                acc[1][ct] = __builtin_amdgcn_mfma_f32_16x16x32_bf16(a1, b, acc[1][ct], 0, 0, 0);
            }
        }
        #pragma unroll
        for (int ct = 0; ct < 4; ct++) {
            int col = nc * 64 + ct * 16 + c;
            int buf = col / 192, cc = col - buf * 192;
            int h = cc >> 5, d = cc & 31;
            bf16_t* outp = (buf == 0) ? qo : ((buf == 1) ? ko : vo);
            float sc = (buf == 0) ? QSCALE : 1.0f;
            float bv = sbias[col];
            #pragma unroll
            for (int rr = 0; rr < 2; rr++)
                #pragma unroll
                for (int r = 0; r < 4; r++) {
                    int row = 32 * s + 16 * rr + 4 * g + r;
                    outp[s_rb[row] + h * 294912 + d] = f2b((acc[rr][ct][r] + bv) * sc);
                }
        }
    }
}

// ---------------------------------------------------------------------------
// Attention via MFMA bf16: 9 waves per (bl,h,w). (unchanged from r4)
// ---------------------------------------------------------------------------
__global__ __launch_bounds__(576, 5) void attn_kernel(
    const bf16_t* __restrict__ qb, const bf16_t* __restrict__ kb,
    const bf16_t* __restrict__ vb, const float* __restrict__ bt,
    bf16_t* __restrict__ ob)
{
    __shared__ bf16_t qlds[144 * 40];
    __shared__ bf16_t klds[144 * 40];
    __shared__ bf16_t vlds[160 * 36];           // rows 144..159 zero
    __shared__ float biaslds[3444];             // bt[:, wi, h]
    __shared__ int eqa[144], ema[144], cnta[144];
    __shared__ bf16_t pscratch[9 * 640];        // per-wave 16 x 40

    const int t   = threadIdx.x;
    const int bid = blockIdx.x;              // ((bl*6 + h)*64 + w)
    const int wi  = bid & 63;
    const int bh  = bid >> 6;
    const int h   = bh % 6;
    const int bl  = bh / 6;
    const int tb  = bid * 4608;
    const int wh  = wi * 6 + h;

    for (int idx = t; idx < 1152; idx += 576) {
        int r = idx >> 3, q4 = (idx & 7) * 4;
        *(ushort4*)(&qlds[r * 40 + q4]) = *(const ushort4*)(qb + tb + r * 32 + q4);
        *(ushort4*)(&klds[r * 40 + q4]) = *(const ushort4*)(kb + tb + r * 32 + q4);
        *(ushort4*)(&vlds[r * 36 + q4]) = *(const ushort4*)(vb + tb + r * 32 + q4);
    }
    vlds[144 * 36 + t] = 0;                      // 16*36 = 576 pad elems
    for (int e = t; e < 3444; e += 576) biaslds[e] = bt[e * 384 + wh];
    if (t < 144) {
        int n = t;
        int w0 = n / 72; int rn = n - w0 * 72;
        int w1 = rn / 12; int w2 = rn - w1 * 12;
        eqa[t] = 828 * w0 + 23 * w1 + w2;
        ema[t] = 1656 * w0 + 138 * w1 + 12 * w2 + 11;
        int npl = wi >> 4, nlat = wi & 15;
        int p0 = npl * 2 + w0, p1 = nlat * 6 + w1, p2 = bl * 12 + w2;
        int sa = (p0 < 6) ? 0 : ((p0 < 7) ? 1 : 2);
        int sb = (p1 < 90) ? 0 : ((p1 < 93) ? 1 : 2);
        int sc = (p2 < 174) ? 0 : 1;
        cnta[t] = sa * 9 + sb * 3 + sc;
    }
    __syncthreads();

    const int s = t / 64;        // wave = strip (0..8)
    const int l = t & 63;
    const int c = l & 15, g = l >> 4;

    // ---- QK^T ----
    f32x4 acc[9];
    short8 aq = *(const short8*)(qlds + (16 * s + c) * 40 + 8 * g);
    #pragma unroll
    for (int kt = 0; kt < 9; kt++) {
        short8 bk = *(const short8*)(klds + (16 * kt + c) * 40 + 8 * g);
        f32x4 z = {0.f, 0.f, 0.f, 0.f};
        acc[kt] = __builtin_amdgcn_mfma_f32_16x16x32_bf16(aq, bk, z, 0, 0, 0);
    }

    // ---- bias + mask ----
    int eqr[4], cnr[4];
    #pragma unroll
    for (int r = 0; r < 4; r++) {
        int R = 16 * s + 4 * g + r;
        eqr[r] = eqa[R]; cnr[r] = cnta[R];
    }
    #pragma unroll
    for (int kt = 0; kt < 9; kt++) {
        int emc = ema[16 * kt + c], cnc = cnta[16 * kt + c];
        #pragma unroll
        for (int r = 0; r < 4; r++)
            acc[kt][r] += biaslds[eqr[r] + emc] + ((cnr[r] == cnc) ? 0.f : -100.f);
    }

    // ---- softmax over 144 cols ----
    float mx[4] = {-1e30f, -1e30f, -1e30f, -1e30f};
    #pragma unroll
    for (int kt = 0; kt < 9; kt++)
        #pragma unroll
        for (int r = 0; r < 4; r++) mx[r] = fmaxf(mx[r], acc[kt][r]);
    #pragma unroll
    for (int r = 0; r < 4; r++) {
        mx[r] = fmaxf(mx[r], __shfl_xor(mx[r], 1));
        mx[r] = fmaxf(mx[r], __shfl_xor(mx[r], 2));
        mx[r] = fmaxf(mx[r], __shfl_xor(mx[r], 4));
        mx[r] = fmaxf(mx[r], __shfl_xor(mx[r], 8));
    }
    float sm[4] = {0.f, 0.f, 0.f, 0.f};
    #pragma unroll
    for (int kt = 0; kt < 9; kt++)
        #pragma unroll
        for (int r = 0; r < 4; r++) {
            float e = __expf(acc[kt][r] - mx[r]);
            acc[kt][r] = e; sm[r] += e;
        }
    #pragma unroll
    for (int r = 0; r < 4; r++) {
        sm[r] += __shfl_xor(sm[r], 1);
        sm[r] += __shfl_xor(sm[r], 2);
        sm[r] += __shfl_xor(sm[r], 4);
        sm[r] += __shfl_xor(sm[r], 8);
        sm[r] = 1.0f / sm[r];
    }

    // ---- PV : O[16 x 32] per wave, K padded to 160 ----
    bf16_t* ps = pscratch + s * 640;
    f32x4 oacc[2] = {{0.f,0.f,0.f,0.f}, {0.f,0.f,0.f,0.f}};
    for (int kc = 0; kc < 5; kc++) {
        #pragma unroll
        for (int tt = 0; tt < 2; tt++) {
            int kt = 2 * kc + tt;
            #pragma unroll
            for (int r = 0; r < 4; r++) {
                float pv = (kt < 9) ? acc[kt][r] * sm[r] : 0.f;
                ps[(4 * g + r) * 40 + tt * 16 + c] = f2b(pv);
            }
        }
        short8 ap = *(const short8*)(ps + c * 40 + 8 * g);
        #pragma unroll
        for (int dt = 0; dt < 2; dt++) {
            union { bf16_t e[8]; short8 v; } bv;
            #pragma unroll
            for (int j = 0; j < 8; j++)
                bv.e[j] = vlds[(kc * 32 + 8 * g + j) * 36 + dt * 16 + c];
            oacc[dt] = __builtin_amdgcn_mfma_f32_16x16x32_bf16(ap, bv.v, oacc[dt], 0, 0, 0);
        }
    }
    #pragma unroll
    for (int dt = 0; dt < 2; dt++)
        #pragma unroll
        for (int r = 0; r < 4; r++)
            ob[tb + (16 * s + 4 * g + r) * 32 + dt * 16 + c] = f2b(oacc[dt][r]);
}

// ---------------------------------------------------------------------------
// Proj via MFMA: A = o bf16 (tiled gather), K=192, N=192. 128 thr, 2x4 blocking.
// Epilogue: xa[orig] = x[orig] + oW + b   (fp32, written to d_out)
// ---------------------------------------------------------------------------
__global__ __launch_bounds__(128) void proj_mfma_kernel(
    const bf16_t* __restrict__ ot, const float* __restrict__ x,
    const bf16_t* __restrict__ wt,  // [192][192] bf16
    const float* __restrict__ pb,
    float* __restrict__ xa)
{
    __shared__ bf16_t Alds[64 * 200];
    __shared__ float sbias[192];
    __shared__ int s_ob[64], s_xb[64];

    const int t = threadIdx.x, m0 = blockIdx.x * 64;
    for (int v = t; v < 192; v += 128) sbias[v] = pb[v];
    if (t < 64) {
        s_ob[t] = tiled_base(m0 + t);
        s_xb[t] = src_off(m0 + t);
    }
    __syncthreads();

    for (int V = t; V < 3072; V += 128) {
        int r = V / 48, c4 = (V - (V / 48) * 48) * 4;
        int h = c4 >> 5, d = c4 & 31;
        *(ushort4*)(&Alds[r * 200 + c4]) = *(const ushort4*)(ot + s_ob[r] + h * 294912 + d);
    }
    __syncthreads();

    const int l = t & 63, s = t >> 6;
    const int c = l & 15, g = l >> 4;
    const bf16_t* arow0 = Alds + (32 * s + c) * 200;
    const bf16_t* arow1 = arow0 + 16 * 200;

    for (int nc = 0; nc < 3; nc++) {
        f32x4 acc[2][4] = {};
        #pragma unroll
        for (int kc = 0; kc < 6; kc++) {
            short8 a0 = *(const short8*)(arow0 + kc * 32 + 8 * g);
            short8 a1 = *(const short8*)(arow1 + kc * 32 + 8 * g);
            #pragma unroll
            for (int ct = 0; ct < 4; ct++) {
                short8 b = *(const short8*)(wt + (nc * 64 + ct * 16 + c) * 192 + kc * 32 + 8 * g);
                acc[0][ct] = __builtin_amdgcn_mfma_f32_16x16x32_bf16(a0, b, acc[0][ct], 0, 0, 0);
                acc[1][ct] = __builtin_amdgcn_mfma_f32_16x16x32_bf16(a1, b, acc[1][ct], 0, 0, 0);
            }
        }
        #pragma unroll
        for (int ct = 0; ct < 4; ct++) {
            int col = nc * 64 + ct * 16 + c;
            float bv = sbias[col];
            #pragma unroll
            for (int rr = 0; rr < 2; rr++)
                #pragma unroll
                for (int r = 0; r < 4; r++) {
                    int row = 32 * s + 16 * rr + 4 * g + r;
                    int off = s_xb[row] + col;
                    xa[off] = acc[rr][ct][r] + bv + x[off];
                }
        }
    }
}

// ---------------------------------------------------------------------------
// Fused MLP: LN2 + FC1 + GELU + FC2 + residual, one 64-row tile per block.
// t-chunks (64 cols) live in wave-private LDS; fc2 accumulates in VGPRs.
// out (=xa in d_out) updated in place.
// ---------------------------------------------------------------------------
__global__ __launch_bounds__(128) void mlp_kernel(
    const float* __restrict__ xa,
    const float* __restrict__ ln2w, const float* __restrict__ ln2b,
    const bf16_t* __restrict__ w1t,    // [768][192]
    const float* __restrict__ b1,
    const bf16_t* __restrict__ w2t,    // [192][768]
    const float* __restrict__ b2,
    float* __restrict__ out)
{
    __shared__ bf16_t Alds[64 * 200];
    __shared__ bf16_t tlds[2][32 * 72];     // per-wave t chunk (32 rows x 64)
    __shared__ float lw[192], lb[192], sb1[768], sb2[192];
    __shared__ float s_mu[64], s_rs[64];

    const int t = threadIdx.x, m0 = blockIdx.x * 64;
    for (int v = t; v < 192; v += 128) { lw[v] = ln2w[v]; lb[v] = ln2b[v]; sb2[v] = b2[v]; }
    for (int v = t; v < 768; v += 128) sb1[v] = b1[v];

    // per-row LN2 stats: 2 threads per row (rows contiguous in xa)
    {
        int r = t >> 1, p = t & 1;
        const float* xr = xa + (m0 + r) * 192 + p * 96;
        float s = 0.f, s2 = 0.f;
        #pragma unroll
        for (int i = 0; i < 24; i++) {
            float4 v = *(const float4*)(xr + i * 4);
            s  += v.x + v.y + v.z + v.w;
            s2 += v.x*v.x + v.y*v.y + v.z*v.z + v.w*v.w;
        }
        s  += __shfl_xor(s, 1);
        s2 += __shfl_xor(s2, 1);
        if (p == 0) {
            float mu  = s * (1.f / 192.f);
            float var = s2 * (1.f / 192.f) - mu * mu;
            s_mu[r] = mu;
            s_rs[r] = 1.0f / sqrtf(var + 1e-5f);
        }
    }
    __syncthreads();

    for (int V = t; V < 3072; V += 128) {
        int r = V / 48, c4 = (V - (V / 48) * 48) * 4;
        float4 a = *(const float4*)(xa + (m0 + r) * 192 + c4);
        float mu = s_mu[r], rs = s_rs[r];
        ushort4 o;
        o.x = f2b((a.x - mu) * rs * lw[c4 + 0] + lb[c4 + 0]);
        o.y = f2b((a.y - mu) * rs * lw[c4 + 1] + lb[c4 + 1]);
        o.z = f2b((a.z - mu) * rs * lw[c4 + 2] + lb[c4 + 2]);
        o.w = f2b((a.w - mu) * rs * lw[c4 + 3] + lb[c4 + 3]);
        *(ushort4*)(&Alds[r * 200 + c4]) = o;
    }
    __syncthreads();

    const int l = t & 63, s = t >> 6;
    const int c = l & 15, g = l >> 4;
    const bf16_t* arow0 = Alds + (32 * s + c) * 200;
    const bf16_t* arow1 = arow0 + 16 * 200;
    bf16_t* tw = tlds[s];

    f32x4 acc2[2][12] = {};
    for (int nc = 0; nc < 12; nc++) {
        // ---- FC1 chunk: 64 cols of t ----
        f32x4 acc1[2][4] = {};
        #pragma unroll
        for (int kc = 0; kc < 6; kc++) {
            short8 a0 = *(const short8*)(arow0 + kc * 32 + 8 * g);
            short8 a1 = *(const short8*)(arow1 + kc * 32 + 8 * g);
            #pragma unroll
            for (int ct = 0; ct < 4; ct++) {
                short8 b = *(const short8*)(w1t + (nc * 64 + ct * 16 + c) * 192 + kc * 32 + 8 * g);
                acc1[0][ct] = __builtin_amdgcn_mfma_f32_16x16x32_bf16(a0, b, acc1[0][ct], 0, 0, 0);
                acc1[1][ct] = __builtin_amdgcn_mfma_f32_16x16x32_bf16(a1, b, acc1[1][ct], 0, 0, 0);
            }
        }
        // ---- GELU -> wave-private LDS (no barrier: same-wave dependence) ----
        #pragma unroll
        for (int ct = 0; ct < 4; ct++) {
            float bv = sb1[nc * 64 + ct * 16 + c];
            #pragma unroll
            for (int rr = 0; rr < 2; rr++)
                #pragma unroll
                for (int r = 0; r < 4; r++)
                    tw[(16 * rr + 4 * g + r) * 72 + ct * 16 + c] =
                        f2b(gelu_exact(acc1[rr][ct][r] + bv));
        }
        // ---- FC2 partial: acc2 += t_chunk @ W2[rows nc*64..] ----
        #pragma unroll
        for (int kh = 0; kh < 2; kh++) {
            short8 a0 = *(const short8*)(tw + c * 72 + kh * 32 + 8 * g);
            short8 a1 = *(const short8*)(tw + (16 + c) * 72 + kh * 32 + 8 * g);
            #pragma unroll
            for (int ct = 0; ct < 12; ct++) {
                short8 b = *(const short8*)(w2t + (ct * 16 + c) * 768 + nc * 64 + kh * 32 + 8 * g);
                acc2[0][ct] = __builtin_amdgcn_mfma_f32_16x16x32_bf16(a0, b, acc2[0][ct], 0, 0, 0);
                acc2[1][ct] = __builtin_amdgcn_mfma_f32_16x16x32_bf16(a1, b, acc2[1][ct], 0, 0, 0);
            }
        }
    }
    // ---- epilogue: out += fc2 + bias (out holds xa) ----
    #pragma unroll
    for (int ct = 0; ct < 12; ct++) {
        int col = ct * 16 + c;
        float bv = sb2[col];
        #pragma unroll
        for (int rr = 0; rr < 2; rr++)
            #pragma unroll
            for (int r = 0; r < 4; r++) {
                int row = m0 + 32 * s + 16 * rr + 4 * g + r;
                int off = row * 192 + col;
                out[off] = acc2[rr][ct][r] + bv + out[off];
            }
    }
}

// ---------------------------------------------------------------------------
extern "C" void kernel_launch(void* const* d_in, const int* in_sizes, int n_in,
                              void* d_out, int out_size, void* d_ws, size_t ws_size,
                              hipStream_t stream)
{
    const float* x      = (const float*)d_in[0];
    const float* ln1w   = (const float*)d_in[1];
    const float* ln1b   = (const float*)d_in[2];
    const float* qkvw   = (const float*)d_in[3];
    const float* qkvb   = (const float*)d_in[4];
    const float* projw  = (const float*)d_in[5];
    const float* projb  = (const float*)d_in[6];
    const float* biast  = (const float*)d_in[7];
    const float* ln2w   = (const float*)d_in[8];
    const float* ln2b   = (const float*)d_in[9];
    const float* fc1w   = (const float*)d_in[10];
    const float* fc1b   = (const float*)d_in[11];
    const float* fc2w   = (const float*)d_in[12];
    const float* fc2b   = (const float*)d_in[13];
    float* out = (float*)d_out;

    // ws: 3 bf16 slots (q->o, k, v) + transposed weights. xa lives in d_out.
    const size_t SLOTB = 53084160;   // 138240*192 bf16 bytes
    char* base = (char*)d_ws;
    bf16_t* qbuf = (bf16_t*)(base);
    bf16_t* kbuf = (bf16_t*)(base + SLOTB);
    bf16_t* vbuf = (bf16_t*)(base + 2 * SLOTB);
    bf16_t* wtq  = (bf16_t*)(base + 3 * SLOTB);   // [576][192]
    bf16_t* wtp  = wtq  + 110592;                 // [192][192]
    bf16_t* wtf1 = wtp  + 36864;                  // [768][192]
    bf16_t* wtf2 = wtf1 + 147456;                 // [192][768]

    wconv_kernel<<<432, 256, 0, stream>>>(qkvw, wtq, 192, 576);
    wconv_kernel<<<144, 256, 0, stream>>>(projw, wtp, 192, 192);
    wconv_kernel<<<576, 256, 0, stream>>>(fc1w, wtf1, 192, 768);
    wconv_kernel<<<576, 256, 0, stream>>>(fc2w, wtf2, 768, 192);

    qkv_mfma_kernel<<<2160, 128, 0, stream>>>(x, ln1w, ln1b, wtq, qkvb, qbuf, kbuf, vbuf);
    attn_kernel<<<5760, 576, 0, stream>>>(qbuf, kbuf, vbuf, biast, qbuf);
    proj_mfma_kernel<<<2160, 128, 0, stream>>>(qbuf, x, wtp, projb, out);
    mlp_kernel<<<2160, 128, 0, stream>>>(out, ln2w, ln2b, wtf1, fc1b, wtf2, fc2b, out);
}

// Round 6
// 955.204 us; speedup vs baseline: 4.1452x; 1.2093x over previous
//
#include <hip/hip_runtime.h>
#include <math.h>

#define DI __device__ __forceinline__

// PL=8 LAT=96 LON=180 C=192 H=6 D=32 ; windows (2,6,12) shift (1,3,6)
// NPL=4 NLAT=16 NLON=15 NW=64 N=144 L=138240 ; BIAS_SIZE=3444
constexpr float QSCALE = 0.17677669529663687f; // 32^-0.5

typedef unsigned short bf16_t;
typedef __attribute__((ext_vector_type(8))) short short8;
typedef __attribute__((ext_vector_type(4))) float f32x4;

DI unsigned short f2b(float f) {            // fp32 -> bf16 bits, RNE
    unsigned u = __builtin_bit_cast(unsigned, f);
    return (unsigned short)((u + 0x7FFFu + ((u >> 16) & 1u)) >> 16);
}

// windowed row -> original token offset (*192), applying forward roll (-1,-3,-6)
DI int src_off(int row) {
    int bl  = row / 9216;  int rem = row - bl * 9216;   // 9216 = 64*144
    int wi  = rem / 144;   int n   = rem - wi * 144;
    int npl = wi >> 4,     nlat = wi & 15;
    int w0  = n / 72;      int rn = n - w0 * 72;
    int w1  = rn / 12;     int w2 = rn - w1 * 12;
    int pl = npl * 2 + w0 + 1;  if (pl >= 8)   pl -= 8;
    int la = nlat * 6 + w1 + 3; if (la >= 96)  la -= 96;
    int lo = bl * 12 + w2 + 6;  if (lo >= 180) lo -= 180;
    return ((pl * 96 + la) * 180 + lo) * 192;
}

DI int tiled_base(int row) {   // windowed row -> q/k/v tiled base (h,d added later)
    int bl = row / 9216; int rem = row - bl * 9216;
    int wi = rem / 144;  int n = rem - wi * 144;
    return bl * 1769472 + wi * 4608 + n * 32;
}

DI float gelu_exact(float v) {
    return 0.5f * v * (1.0f + erff(v * 0.70710678118654752440f));
}

// ---------------------------------------------------------------------------
// Weight transpose + bf16 convert: src fp32 [K][N] -> dst bf16 [N][K]
// ---------------------------------------------------------------------------
__global__ __launch_bounds__(256) void wconv_kernel(
    const float* __restrict__ src, bf16_t* __restrict__ dst, int K, int N)
{
    int i = blockIdx.x * 256 + threadIdx.x;
    if (i < K * N) {
        int n = i / K, k = i - n * K;
        dst[i] = f2b(src[k * N + n]);
    }
}

// ---------------------------------------------------------------------------
// QKV via MFMA: LN1 fused, A held in registers (each lane: row c of its
// wave's 16-row strip, all K). W chunk (64 cols x 192) staged in LDS per nc.
// 256 thr / 4 waves, M-tile 64.
// ---------------------------------------------------------------------------
__global__ __launch_bounds__(256, 4) void qkv_mfma_kernel(
    const float* __restrict__ x,
    const float* __restrict__ ln1w, const float* __restrict__ ln1b,
    const bf16_t* __restrict__ wt,   // [576][192] bf16
    const float* __restrict__ bias,  // [576]
    bf16_t* __restrict__ qo, bf16_t* __restrict__ ko, bf16_t* __restrict__ vo)
{
    __shared__ bf16_t Wlds[64 * 200];
    __shared__ float lw[192], lb[192], sbias[576];

    const int t  = threadIdx.x;
    const int m0 = blockIdx.x * 64;

    for (int v = t; v < 192; v += 256) { lw[v] = ln1w[v]; lb[v] = ln1b[v]; }
    for (int v = t; v < 576; v += 256) sbias[v] = bias[v];

    const int l = t & 63, wv = t >> 6;     // wave wv owns rows 16wv..16wv+15
    const int c = l & 15, g = l >> 4;      // lane = 16g + c
    const int msrc = src_off(m0 + 16 * wv + c);

    // load row c (48 elems per lane: k = kc*32+8g+j), LN stats over 4 g-lanes
    float fa[6][8];
    float ss = 0.f, s2 = 0.f;
    #pragma unroll
    for (int kc = 0; kc < 6; kc++) {
        float4 v0 = *(const float4*)(x + msrc + kc * 32 + 8 * g);
        float4 v1 = *(const float4*)(x + msrc + kc * 32 + 8 * g + 4);
        fa[kc][0]=v0.x; fa[kc][1]=v0.y; fa[kc][2]=v0.z; fa[kc][3]=v0.w;
        fa[kc][4]=v1.x; fa[kc][5]=v1.y; fa[kc][6]=v1.z; fa[kc][7]=v1.w;
        ss += v0.x+v0.y+v0.z+v0.w + v1.x+v1.y+v1.z+v1.w;
        s2 += v0.x*v0.x+v0.y*v0.y+v0.z*v0.z+v0.w*v0.w
            + v1.x*v1.x+v1.y*v1.y+v1.z*v1.z+v1.w*v1.w;
    }
    ss += __shfl_xor(ss, 16); s2 += __shfl_xor(s2, 16);
    ss += __shfl_xor(ss, 32); s2 += __shfl_xor(s2, 32);
    float mu = ss * (1.f / 192.f);
    float rs = 1.0f / sqrtf(s2 * (1.f / 192.f) - mu * mu + 1e-5f);
    __syncthreads();                        // lw/lb staged

    short8 a[6];
    #pragma unroll
    for (int kc = 0; kc < 6; kc++) {
        union { bf16_t e[8]; short8 v; } u;
        #pragma unroll
        for (int j = 0; j < 8; j++) {
            int col = kc * 32 + 8 * g + j;
            u.e[j] = f2b((fa[kc][j] - mu) * rs * lw[col] + lb[col]);
        }
        a[kc] = u.v;
    }

    int rb4[4];
    #pragma unroll
    for (int r = 0; r < 4; r++) rb4[r] = tiled_base(m0 + 16 * wv + 4 * g + r);

    for (int nc = 0; nc < 9; nc++) {
        __syncthreads();                    // prev chunk consumed
        for (int V = t; V < 3072; V += 256) {
            int row = V / 48, q = (V - row * 48) * 4;
            *(ushort4*)(&Wlds[row * 200 + q]) =
                *(const ushort4*)(wt + (nc * 64 + row) * 192 + q);
        }
        __syncthreads();
        f32x4 acc[4] = {};
        #pragma unroll
        for (int kc = 0; kc < 6; kc++)
            #pragma unroll
            for (int ct = 0; ct < 4; ct++) {
                short8 b = *(const short8*)(&Wlds[(ct * 16 + c) * 200 + kc * 32 + 8 * g]);
                acc[ct] = __builtin_amdgcn_mfma_f32_16x16x32_bf16(a[kc], b, acc[ct], 0, 0, 0);
            }
        #pragma unroll
        for (int ct = 0; ct < 4; ct++) {
            int col = nc * 64 + ct * 16 + c;
            int buf = col / 192, cc = col - buf * 192;
            int h = cc >> 5, d = cc & 31;
            bf16_t* outp = (buf == 0) ? qo : ((buf == 1) ? ko : vo);
            float sc = (buf == 0) ? QSCALE : 1.0f;
            float bv = sbias[col];
            #pragma unroll
            for (int r = 0; r < 4; r++)
                outp[rb4[r] + h * 294912 + d] = f2b((acc[ct][r] + bv) * sc);
        }
    }
}

// ---------------------------------------------------------------------------
// Attention via MFMA bf16: 9 waves per (bl,h,w). (unchanged)
// ---------------------------------------------------------------------------
__global__ __launch_bounds__(576, 5) void attn_kernel(
    const bf16_t* __restrict__ qb, const bf16_t* __restrict__ kb,
    const bf16_t* __restrict__ vb, const float* __restrict__ bt,
    bf16_t* __restrict__ ob)
{
    __shared__ bf16_t qlds[144 * 40];
    __shared__ bf16_t klds[144 * 40];
    __shared__ bf16_t vlds[160 * 36];           // rows 144..159 zero
    __shared__ float biaslds[3444];             // bt[:, wi, h]
    __shared__ int eqa[144], ema[144], cnta[144];
    __shared__ bf16_t pscratch[9 * 640];        // per-wave 16 x 40

    const int t   = threadIdx.x;
    const int bid = blockIdx.x;              // ((bl*6 + h)*64 + w)
    const int wi  = bid & 63;
    const int bh  = bid >> 6;
    const int h   = bh % 6;
    const int bl  = bh / 6;
    const int tb  = bid * 4608;
    const int wh  = wi * 6 + h;

    for (int idx = t; idx < 1152; idx += 576) {
        int r = idx >> 3, q4 = (idx & 7) * 4;
        *(ushort4*)(&qlds[r * 40 + q4]) = *(const ushort4*)(qb + tb + r * 32 + q4);
        *(ushort4*)(&klds[r * 40 + q4]) = *(const ushort4*)(kb + tb + r * 32 + q4);
        *(ushort4*)(&vlds[r * 36 + q4]) = *(const ushort4*)(vb + tb + r * 32 + q4);
    }
    vlds[144 * 36 + t] = 0;                      // 16*36 = 576 pad elems
    for (int e = t; e < 3444; e += 576) biaslds[e] = bt[e * 384 + wh];
    if (t < 144) {
        int n = t;
        int w0 = n / 72; int rn = n - w0 * 72;
        int w1 = rn / 12; int w2 = rn - w1 * 12;
        eqa[t] = 828 * w0 + 23 * w1 + w2;
        ema[t] = 1656 * w0 + 138 * w1 + 12 * w2 + 11;
        int npl = wi >> 4, nlat = wi & 15;
        int p0 = npl * 2 + w0, p1 = nlat * 6 + w1, p2 = bl * 12 + w2;
        int sa = (p0 < 6) ? 0 : ((p0 < 7) ? 1 : 2);
        int sb = (p1 < 90) ? 0 : ((p1 < 93) ? 1 : 2);
        int sc = (p2 < 174) ? 0 : 1;
        cnta[t] = sa * 9 + sb * 3 + sc;
    }
    __syncthreads();

    const int s = t / 64;        // wave = strip (0..8)
    const int l = t & 63;
    const int c = l & 15, g = l >> 4;

    // ---- QK^T ----
    f32x4 acc[9];
    short8 aq = *(const short8*)(qlds + (16 * s + c) * 40 + 8 * g);
    #pragma unroll
    for (int kt = 0; kt < 9; kt++) {
        short8 bk = *(const short8*)(klds + (16 * kt + c) * 40 + 8 * g);
        f32x4 z = {0.f, 0.f, 0.f, 0.f};
        acc[kt] = __builtin_amdgcn_mfma_f32_16x16x32_bf16(aq, bk, z, 0, 0, 0);
    }

    // ---- bias + mask ----
    int eqr[4], cnr[4];
    #pragma unroll
    for (int r = 0; r < 4; r++) {
        int R = 16 * s + 4 * g + r;
        eqr[r] = eqa[R]; cnr[r] = cnta[R];
    }
    #pragma unroll
    for (int kt = 0; kt < 9; kt++) {
        int emc = ema[16 * kt + c], cnc = cnta[16 * kt + c];
        #pragma unroll
        for (int r = 0; r < 4; r++)
            acc[kt][r] += biaslds[eqr[r] + emc] + ((cnr[r] == cnc) ? 0.f : -100.f);
    }

    // ---- softmax over 144 cols ----
    float mx[4] = {-1e30f, -1e30f, -1e30f, -1e30f};
    #pragma unroll
    for (int kt = 0; kt < 9; kt++)
        #pragma unroll
        for (int r = 0; r < 4; r++) mx[r] = fmaxf(mx[r], acc[kt][r]);
    #pragma unroll
    for (int r = 0; r < 4; r++) {
        mx[r] = fmaxf(mx[r], __shfl_xor(mx[r], 1));
        mx[r] = fmaxf(mx[r], __shfl_xor(mx[r], 2));
        mx[r] = fmaxf(mx[r], __shfl_xor(mx[r], 4));
        mx[r] = fmaxf(mx[r], __shfl_xor(mx[r], 8));
    }
    float sm[4] = {0.f, 0.f, 0.f, 0.f};
    #pragma unroll
    for (int kt = 0; kt < 9; kt++)
        #pragma unroll
        for (int r = 0; r < 4; r++) {
            float e = __expf(acc[kt][r] - mx[r]);
            acc[kt][r] = e; sm[r] += e;
        }
    #pragma unroll
    for (int r = 0; r < 4; r++) {
        sm[r] += __shfl_xor(sm[r], 1);
        sm[r] += __shfl_xor(sm[r], 2);
        sm[r] += __shfl_xor(sm[r], 4);
        sm[r] += __shfl_xor(sm[r], 8);
        sm[r] = 1.0f / sm[r];
    }

    // ---- PV : O[16 x 32] per wave, K padded to 160 ----
    bf16_t* ps = pscratch + s * 640;
    f32x4 oacc[2] = {{0.f,0.f,0.f,0.f}, {0.f,0.f,0.f,0.f}};
    for (int kc = 0; kc < 5; kc++) {
        #pragma unroll
        for (int tt = 0; tt < 2; tt++) {
            int kt = 2 * kc + tt;
            #pragma unroll
            for (int r = 0; r < 4; r++) {
                float pv = (kt < 9) ? acc[kt][r] * sm[r] : 0.f;
                ps[(4 * g + r) * 40 + tt * 16 + c] = f2b(pv);
            }
        }
        short8 ap = *(const short8*)(ps + c * 40 + 8 * g);
        #pragma unroll
        for (int dt = 0; dt < 2; dt++) {
            union { bf16_t e[8]; short8 v; } bv;
            #pragma unroll
            for (int j = 0; j < 8; j++)
                bv.e[j] = vlds[(kc * 32 + 8 * g + j) * 36 + dt * 16 + c];
            oacc[dt] = __builtin_amdgcn_mfma_f32_16x16x32_bf16(ap, bv.v, oacc[dt], 0, 0, 0);
        }
    }
    #pragma unroll
    for (int dt = 0; dt < 2; dt++)
        #pragma unroll
        for (int r = 0; r < 4; r++)
            ob[tb + (16 * s + 4 * g + r) * 32 + dt * 16 + c] = f2b(oacc[dt][r]);
}

// ---------------------------------------------------------------------------
// Proj via MFMA: A = o bf16 (tiled gather), K=192, N=192. 128 thr, 2x4 blocking.
// Epilogue: xa[orig] = x[orig] + oW + b   (fp32, written to d_out)
// ---------------------------------------------------------------------------
__global__ __launch_bounds__(128) void proj_mfma_kernel(
    const bf16_t* __restrict__ ot, const float* __restrict__ x,
    const bf16_t* __restrict__ wt,  // [192][192] bf16
    const float* __restrict__ pb,
    float* __restrict__ xa)
{
    __shared__ bf16_t Alds[64 * 200];
    __shared__ float sbias[192];
    __shared__ int s_ob[64], s_xb[64];

    const int t = threadIdx.x, m0 = blockIdx.x * 64;
    for (int v = t; v < 192; v += 128) sbias[v] = pb[v];
    if (t < 64) {
        s_ob[t] = tiled_base(m0 + t);
        s_xb[t] = src_off(m0 + t);
    }
    __syncthreads();

    for (int V = t; V < 3072; V += 128) {
        int r = V / 48, c4 = (V - (V / 48) * 48) * 4;
        int h = c4 >> 5, d = c4 & 31;
        *(ushort4*)(&Alds[r * 200 + c4]) = *(const ushort4*)(ot + s_ob[r] + h * 294912 + d);
    }
    __syncthreads();

    const int l = t & 63, s = t >> 6;
    const int c = l & 15, g = l >> 4;
    const bf16_t* arow0 = Alds + (32 * s + c) * 200;
    const bf16_t* arow1 = arow0 + 16 * 200;

    for (int nc = 0; nc < 3; nc++) {
        f32x4 acc[2][4] = {};
        #pragma unroll
        for (int kc = 0; kc < 6; kc++) {
            short8 a0 = *(const short8*)(arow0 + kc * 32 + 8 * g);
            short8 a1 = *(const short8*)(arow1 + kc * 32 + 8 * g);
            #pragma unroll
            for (int ct = 0; ct < 4; ct++) {
                short8 b = *(const short8*)(wt + (nc * 64 + ct * 16 + c) * 192 + kc * 32 + 8 * g);
                acc[0][ct] = __builtin_amdgcn_mfma_f32_16x16x32_bf16(a0, b, acc[0][ct], 0, 0, 0);
                acc[1][ct] = __builtin_amdgcn_mfma_f32_16x16x32_bf16(a1, b, acc[1][ct], 0, 0, 0);
            }
        }
        #pragma unroll
        for (int ct = 0; ct < 4; ct++) {
            int col = nc * 64 + ct * 16 + c;
            float bv = sbias[col];
            #pragma unroll
            for (int rr = 0; rr < 2; rr++)
                #pragma unroll
                for (int r = 0; r < 4; r++) {
                    int row = 32 * s + 16 * rr + 4 * g + r;
                    int off = s_xb[row] + col;
                    xa[off] = acc[rr][ct][r] + bv + x[off];
                }
        }
    }
}

// ---------------------------------------------------------------------------
// Fused MLP: LN2 + FC1 + GELU + FC2 + residual. 256 thr / 4 waves, M-tile 64.
// A (LN2'd x) in registers; W1/W2 64-wide chunks share one LDS buffer
// (4 barriers per nc); t in wave-private LDS; acc2[12] in VGPRs.
// ---------------------------------------------------------------------------
__global__ __launch_bounds__(256, 3) void mlp_kernel(
    const float* __restrict__ xa,
    const float* __restrict__ ln2w, const float* __restrict__ ln2b,
    const bf16_t* __restrict__ w1t,    // [768][192]
    const float* __restrict__ b1,
    const bf16_t* __restrict__ w2t,    // [192][768]
    const float* __restrict__ b2,
    float* __restrict__ out)
{
    __shared__ bf16_t wbuf[13824];          // max(64*200, 192*72) elems
    __shared__ bf16_t tlds[4][16 * 72];     // per-wave t chunk (16 x 64, pad 72)
    __shared__ float lw[192], lb[192], sb1[768], sb2[192];

    const int t = threadIdx.x, m0 = blockIdx.x * 64;
    for (int v = t; v < 192; v += 256) { lw[v]=ln2w[v]; lb[v]=ln2b[v]; sb2[v]=b2[v]; }
    for (int v = t; v < 768; v += 256) sb1[v] = b1[v];

    const int l = t & 63, wv = t >> 6;
    const int c = l & 15, g = l >> 4;
    const float* xr = xa + (m0 + 16 * wv + c) * 192;

    float fa[6][8];
    float ss = 0.f, s2 = 0.f;
    #pragma unroll
    for (int kc = 0; kc < 6; kc++) {
        float4 v0 = *(const float4*)(xr + kc * 32 + 8 * g);
        float4 v1 = *(const float4*)(xr + kc * 32 + 8 * g + 4);
        fa[kc][0]=v0.x; fa[kc][1]=v0.y; fa[kc][2]=v0.z; fa[kc][3]=v0.w;
        fa[kc][4]=v1.x; fa[kc][5]=v1.y; fa[kc][6]=v1.z; fa[kc][7]=v1.w;
        ss += v0.x+v0.y+v0.z+v0.w + v1.x+v1.y+v1.z+v1.w;
        s2 += v0.x*v0.x+v0.y*v0.y+v0.z*v0.z+v0.w*v0.w
            + v1.x*v1.x+v1.y*v1.y+v1.z*v1.z+v1.w*v1.w;
    }
    ss += __shfl_xor(ss, 16); s2 += __shfl_xor(s2, 16);
    ss += __shfl_xor(ss, 32); s2 += __shfl_xor(s2, 32);
    float mu = ss * (1.f / 192.f);
    float rs = 1.0f / sqrtf(s2 * (1.f / 192.f) - mu * mu + 1e-5f);
    __syncthreads();                        // lw/lb staged

    short8 a[6];
    #pragma unroll
    for (int kc = 0; kc < 6; kc++) {
        union { bf16_t e[8]; short8 v; } u;
        #pragma unroll
        for (int j = 0; j < 8; j++) {
            int col = kc * 32 + 8 * g + j;
            u.e[j] = f2b((fa[kc][j] - mu) * rs * lw[col] + lb[col]);
        }
        a[kc] = u.v;
    }

    bf16_t* tw = tlds[wv];
    f32x4 acc2[12] = {};

    for (int nc = 0; nc < 12; nc++) {
        __syncthreads();                    // wbuf free (prev FC2 done)
        for (int V = t; V < 3072; V += 256) {   // stage W1 chunk [64][192]->[r*200]
            int row = V / 48, q = (V - row * 48) * 4;
            *(ushort4*)(&wbuf[row * 200 + q]) =
                *(const ushort4*)(w1t + (nc * 64 + row) * 192 + q);
        }
        __syncthreads();
        // ---- FC1 chunk ----
        f32x4 acc1[4] = {};
        #pragma unroll
        for (int kc = 0; kc < 6; kc++)
            #pragma unroll
            for (int ct = 0; ct < 4; ct++) {
                short8 b = *(const short8*)(&wbuf[(ct * 16 + c) * 200 + kc * 32 + 8 * g]);
                acc1[ct] = __builtin_amdgcn_mfma_f32_16x16x32_bf16(a[kc], b, acc1[ct], 0, 0, 0);
            }
        // ---- GELU -> wave-private t ----
        #pragma unroll
        for (int ct = 0; ct < 4; ct++) {
            float bv = sb1[nc * 64 + ct * 16 + c];
            #pragma unroll
            for (int r = 0; r < 4; r++)
                tw[(4 * g + r) * 72 + ct * 16 + c] = f2b(gelu_exact(acc1[ct][r] + bv));
        }
        __syncthreads();                    // all waves done reading W1
        for (int V = t; V < 3072; V += 256) {   // stage W2 chunk [192][64]->[r*72]
            int row = V >> 4, q = (V & 15) * 4;
            *(ushort4*)(&wbuf[row * 72 + q]) =
                *(const ushort4*)(w2t + row * 768 + nc * 64 + q);
        }
        __syncthreads();
        // ---- FC2 partial ----
        #pragma unroll
        for (int kh = 0; kh < 2; kh++) {
            short8 at = *(const short8*)(&tw[c * 72 + kh * 32 + 8 * g]);
            #pragma unroll
            for (int ct = 0; ct < 12; ct++) {
                short8 b = *(const short8*)(&wbuf[(ct * 16 + c) * 72 + kh * 32 + 8 * g]);
                acc2[ct] = __builtin_amdgcn_mfma_f32_16x16x32_bf16(at, b, acc2[ct], 0, 0, 0);
            }
        }
    }
    // ---- epilogue: out += fc2 + bias (out holds xa) ----
    #pragma unroll
    for (int ct = 0; ct < 12; ct++) {
        int col = ct * 16 + c;
        float bv = sb2[col];
        #pragma unroll
        for (int r = 0; r < 4; r++) {
            int off = (m0 + 16 * wv + 4 * g + r) * 192 + col;
            out[off] = acc2[ct][r] + bv + out[off];
        }
    }
}

// ---------------------------------------------------------------------------
extern "C" void kernel_launch(void* const* d_in, const int* in_sizes, int n_in,
                              void* d_out, int out_size, void* d_ws, size_t ws_size,
                              hipStream_t stream)
{
    const float* x      = (const float*)d_in[0];
    const float* ln1w   = (const float*)d_in[1];
    const float* ln1b   = (const float*)d_in[2];
    const float* qkvw   = (const float*)d_in[3];
    const float* qkvb   = (const float*)d_in[4];
    const float* projw  = (const float*)d_in[5];
    const float* projb  = (const float*)d_in[6];
    const float* biast  = (const float*)d_in[7];
    const float* ln2w   = (const float*)d_in[8];
    const float* ln2b   = (const float*)d_in[9];
    const float* fc1w   = (const float*)d_in[10];
    const float* fc1b   = (const float*)d_in[11];
    const float* fc2w   = (const float*)d_in[12];
    const float* fc2b   = (const float*)d_in[13];
    float* out = (float*)d_out;

    // ws: 3 bf16 slots (q->o, k, v) + transposed weights. xa lives in d_out.
    const size_t SLOTB = 53084160;   // 138240*192 bf16 bytes
    char* base = (char*)d_ws;
    bf16_t* qbuf = (bf16_t*)(base);
    bf16_t* kbuf = (bf16_t*)(base + SLOTB);
    bf16_t* vbuf = (bf16_t*)(base + 2 * SLOTB);
    bf16_t* wtq  = (bf16_t*)(base + 3 * SLOTB);   // [576][192]
    bf16_t* wtp  = wtq  + 110592;                 // [192][192]
    bf16_t* wtf1 = wtp  + 36864;                  // [768][192]
    bf16_t* wtf2 = wtf1 + 147456;                 // [192][768]

    wconv_kernel<<<432, 256, 0, stream>>>(qkvw, wtq, 192, 576);
    wconv_kernel<<<144, 256, 0, stream>>>(projw, wtp, 192, 192);
    wconv_kernel<<<576, 256, 0, stream>>>(fc1w, wtf1, 192, 768);
    wconv_kernel<<<576, 256, 0, stream>>>(fc2w, wtf2, 768, 192);

    qkv_mfma_kernel<<<2160, 256, 0, stream>>>(x, ln1w, ln1b, wtq, qkvb, qbuf, kbuf, vbuf);
    attn_kernel<<<5760, 576, 0, stream>>>(qbuf, kbuf, vbuf, biast, qbuf);
    proj_mfma_kernel<<<2160, 128, 0, stream>>>(qbuf, x, wtp, projb, out);
    mlp_kernel<<<2160, 256, 0, stream>>>(out, ln2w, ln2b, wtf1, fc1b, wtf2, fc2b, out);
}